// Round 9
// baseline (555.297 us; speedup 1.0000x reference)
//
#include <hip/hip_runtime.h>
#include <hip/hip_fp16.h>
#include <math.h>

#define N_NODES 50000
#define N_EDGES 1600000
#define N_GRAPHS 512
#define F_IN 9
#define H 64
#define SCAN_BLOCK 1024
#define N_CHUNKS ((N_NODES + SCAN_BLOCK - 1) / SCAN_BLOCK)   // 49

// ---------- prep: block 0 transposes weights, blocks >=1 histogram dst ----------
__global__ void prep_kernel(const int* __restrict__ ei, int* __restrict__ deg,
                            const float* __restrict__ w1a,
                            const float* __restrict__ w1b,
                            const float* __restrict__ w2a,
                            const float* __restrict__ w2b,
                            const float* __restrict__ wr1,
                            float* __restrict__ w1aT,
                            float* __restrict__ w1bT,
                            float* __restrict__ w2aT,
                            float* __restrict__ w2bT,
                            float* __restrict__ wr1T) {
    if (blockIdx.x == 0) {
        int t = threadIdx.x;
        for (int i = t; i < H * F_IN; i += 256) {
            int f = i / F_IN, k = i % F_IN;
            w1aT[k * H + f] = w1a[i];
        }
        for (int i = t; i < H * H; i += 256) {
            int f = i / H, k = i % H;
            w1bT[k * H + f] = w1b[i];
            w2aT[k * H + f] = w2a[i];
            w2bT[k * H + f] = w2b[i];
        }
        for (int i = t; i < 32 * H; i += 256) {
            int f = i / H, k = i % H;
            wr1T[k * 32 + f] = wr1[i];
        }
        return;
    }
    int t = (blockIdx.x - 1) * blockDim.x + threadIdx.x;
    if (t >= N_EDGES / 4) return;
    int4 d4 = ((const int4*)(ei + N_EDGES))[t];
    atomicAdd(&deg[d4.x], 1);
    atomicAdd(&deg[d4.y], 1);
    atomicAdd(&deg[d4.z], 1);
    atomicAdd(&deg[d4.w], 1);
}

__global__ void scan_local(const int* __restrict__ deg,
                           int* __restrict__ starts,
                           int* __restrict__ csum) {
    __shared__ int wsum[16];
    __shared__ int woff[16];
    int tid = threadIdx.x, lane = tid & 63, wid = tid >> 6;
    int i = blockIdx.x * SCAN_BLOCK + tid;
    int v = (i < N_NODES) ? deg[i] : 0;
    int incl = v;
#pragma unroll
    for (int off = 1; off < 64; off <<= 1) {
        int t = __shfl_up(incl, off, 64);
        if (lane >= off) incl += t;
    }
    if (lane == 63) wsum[wid] = incl;
    __syncthreads();
    if (wid == 0) {
        int wv = (lane < 16) ? wsum[lane] : 0;
        int winc = wv;
#pragma unroll
        for (int off = 1; off < 16; off <<= 1) {
            int t = __shfl_up(winc, off, 64);
            if (lane >= off) winc += t;
        }
        if (lane < 16) woff[lane] = winc - wv;
    }
    __syncthreads();
    if (i < N_NODES) starts[i] = woff[wid] + (incl - v);
    if (tid == 0) csum[blockIdx.x] = woff[15] + wsum[15];
}

__global__ void scan_top(const int* __restrict__ csum, int* __restrict__ coff) {
    int lane = threadIdx.x;
    int v = (lane < N_CHUNKS) ? csum[lane] : 0;
    int incl = v;
#pragma unroll
    for (int off = 1; off < 64; off <<= 1) {
        int t = __shfl_up(incl, off, 64);
        if (lane >= off) incl += t;
    }
    if (lane < N_CHUNKS) coff[lane] = incl - v;
}

__global__ void scan_add(int* __restrict__ starts, int* __restrict__ next,
                         const int* __restrict__ coff) {
    int i = blockIdx.x * SCAN_BLOCK + threadIdx.x;
    if (i >= N_NODES) return;
    int s = starts[i] + coff[blockIdx.x];
    starts[i] = s;
    next[i] = s;
}

// pack (src:16 | attr:fp16) into 4B -> halves payload traffic everywhere
__global__ void scatter_kernel(const int* __restrict__ ei,
                               const float* __restrict__ ea,
                               int* __restrict__ next,
                               unsigned* __restrict__ ep4) {
    int e = blockIdx.x * blockDim.x + threadIdx.x;
    if (e >= N_EDGES) return;
    int d = ei[N_EDGES + e];
    int pos = atomicAdd(&next[d], 1);
    unsigned pv = ((unsigned)ei[e] << 16) |
                  (unsigned)__half_as_ushort(__float2half(ea[e]));
    ep4[pos] = pv;
}

#define UNPACK_ATTR(P) __half2float(__ushort_as_half((unsigned short)((P) & 0xffffu)))

// ---------- conv1 fused: aggregation (4 slots x 16 lanes, unroll 4) + MLP;
// h1 written as two feature-split halves (32 feats each, 64B rows) ----------
__global__ void conv1_kernel(const float* __restrict__ x,
                             const int* __restrict__ starts,
                             const int* __restrict__ deg,
                             const unsigned* __restrict__ ep4,
                             const float* __restrict__ e1w,
                             const float* __restrict__ e1b,
                             const float* __restrict__ w1aT,
                             const float* __restrict__ b1a,
                             const float* __restrict__ w1bT,
                             const float* __restrict__ b1b,
                             __half* __restrict__ h1lo,
                             __half* __restrict__ h1hi) {
    int n = blockIdx.x * (blockDim.x >> 6) + (threadIdx.x >> 6);
    int lane = threadIdx.x & 63;
    if (n >= N_NODES) return;
    int slot = lane >> 4;
    int f = lane & 15;
    int s0 = starts[n], dg = deg[n];
    bool act = f < F_IN;
    float wf = act ? e1w[f] : 0.f;
    float bf = act ? e1b[f] : 0.f;
    float acc = 0.f;
    int j = slot;
    for (; j + 12 < dg; j += 16) {
        unsigned pa = ep4[s0 + j];
        unsigned pb = ep4[s0 + j + 4];
        unsigned pc = ep4[s0 + j + 8];
        unsigned pd = ep4[s0 + j + 12];
        float xa_ = act ? x[(pa >> 16) * F_IN + f] : 0.f;
        float xb_ = act ? x[(pb >> 16) * F_IN + f] : 0.f;
        float xc_ = act ? x[(pc >> 16) * F_IN + f] : 0.f;
        float xd_ = act ? x[(pd >> 16) * F_IN + f] : 0.f;
        if (act) {
            acc += fmaxf(xa_ + UNPACK_ATTR(pa) * wf + bf, 0.f)
                 + fmaxf(xb_ + UNPACK_ATTR(pb) * wf + bf, 0.f)
                 + fmaxf(xc_ + UNPACK_ATTR(pc) * wf + bf, 0.f)
                 + fmaxf(xd_ + UNPACK_ATTR(pd) * wf + bf, 0.f);
        }
    }
    for (; j < dg; j += 4) {
        unsigned p = ep4[s0 + j];
        float xv = act ? x[(p >> 16) * F_IN + f] : 0.f;
        float m = xv + UNPACK_ATTR(p) * wf + bf;
        acc += act ? fmaxf(m, 0.f) : 0.f;
    }
    acc += __shfl_xor(acc, 16, 64);
    acc += __shfl_xor(acc, 32, 64);
    float xa = (lane < F_IN) ? x[n * F_IN + lane] + acc : 0.f;
    float a1 = b1a[lane];
#pragma unroll
    for (int k = 0; k < F_IN; ++k)
        a1 += __shfl(xa, k, 64) * w1aT[k * H + lane];
    float ha = fmaxf(a1, 0.f);
    float a2 = b1b[lane];
#pragma unroll 16
    for (int k = 0; k < H; ++k)
        a2 += __shfl(ha, k, 64) * w1bT[k * H + lane];
    __half hv = __float2half(fmaxf(a2, 0.f));
    if (lane < 32) h1lo[n * 32 + lane] = hv;
    else           h1hi[n * 32 + (lane - 32)] = hv;
}

// ---------- one conv2 aggregation phase as its OWN LAUNCH: the gathered
// half-array (3.2MB) fits per-XCD L2, so steady-state gathers are L2 hits.
// lane = half*32 + fh : half = edge parity, fh = feature in the 32-block ----------
__global__ void aggphase_kernel(const __half* __restrict__ harr,
                                const int* __restrict__ starts,
                                const int* __restrict__ deg,
                                const unsigned* __restrict__ ep4,
                                const float* __restrict__ ew,   // 32 floats
                                const float* __restrict__ eb,   // 32 floats
                                float* __restrict__ aggout) {   // [N][32] fp32
    int n = blockIdx.x * (blockDim.x >> 6) + (threadIdx.x >> 6);
    int lane = threadIdx.x & 63;
    if (n >= N_NODES) return;
    int half = lane >> 5;
    int fh = lane & 31;
    int s0 = starts[n], dg = deg[n];
    const unsigned* ep = ep4 + s0;
    float wf = ew[fh], bf = eb[fh];
    float acc = 0.f;
    int j = 0;
#define EDGE1(P, V) acc += fmaxf((V) + UNPACK_ATTR(P) * wf + bf, 0.f)
    for (; j + 16 <= dg; j += 16) {   // 8 gathers in flight = 16 edges
        unsigned p0 = ep[j +  0 + half], p1 = ep[j +  2 + half];
        unsigned p2 = ep[j +  4 + half], p3 = ep[j +  6 + half];
        unsigned p4 = ep[j +  8 + half], p5 = ep[j + 10 + half];
        unsigned p6 = ep[j + 12 + half], p7 = ep[j + 14 + half];
        float v0 = __half2float(harr[(p0 >> 16) * 32 + fh]);
        float v1 = __half2float(harr[(p1 >> 16) * 32 + fh]);
        float v2 = __half2float(harr[(p2 >> 16) * 32 + fh]);
        float v3 = __half2float(harr[(p3 >> 16) * 32 + fh]);
        float v4 = __half2float(harr[(p4 >> 16) * 32 + fh]);
        float v5 = __half2float(harr[(p5 >> 16) * 32 + fh]);
        float v6 = __half2float(harr[(p6 >> 16) * 32 + fh]);
        float v7 = __half2float(harr[(p7 >> 16) * 32 + fh]);
        EDGE1(p0, v0); EDGE1(p1, v1); EDGE1(p2, v2); EDGE1(p3, v3);
        EDGE1(p4, v4); EDGE1(p5, v5); EDGE1(p6, v6); EDGE1(p7, v7);
    }
    for (; j + 2 <= dg; j += 2) {
        unsigned p = ep[j + half];
        float v = __half2float(harr[(p >> 16) * 32 + fh]);
        EDGE1(p, v);
    }
    if (j < dg && half == 0) {
        unsigned p = ep[j];
        float v = __half2float(harr[(p >> 16) * 32 + fh]);
        EDGE1(p, v);
    }
#undef EDGE1
    acc += __shfl_xor(acc, 32, 64);
    if (half == 0) aggout[n * 32 + fh] = acc;
}

// ---------- node MLP + readout (reads h1 halves + fp32 aggregates) ----------
__global__ void node2_kernel(const __half* __restrict__ h1lo,
                             const __half* __restrict__ h1hi,
                             const float* __restrict__ aggA,
                             const float* __restrict__ aggB,
                             const float* __restrict__ w2aT,
                             const float* __restrict__ b2a,
                             const float* __restrict__ w2bT,
                             const float* __restrict__ b2b,
                             const float* __restrict__ wr1T,
                             const float* __restrict__ br1,
                             const float* __restrict__ wr2,
                             const float* __restrict__ br2,
                             const int* __restrict__ term,
                             const float* __restrict__ ccost,
                             const int* __restrict__ batch,
                             float* __restrict__ pi,
                             float* __restrict__ te) {
    int n = blockIdx.x * (blockDim.x >> 6) + (threadIdx.x >> 6);
    int f = threadIdx.x & 63;
    if (n >= N_NODES) return;
    int fh = f & 31;
    float hv = (f < 32) ? __half2float(h1lo[n * 32 + fh])
                        : __half2float(h1hi[n * 32 + fh]);
    float ag = (f < 32) ? aggA[n * 32 + fh] : aggB[n * 32 + fh];
    float h = hv + ag;
    float m1 = b2a[f];
#pragma unroll 16
    for (int k = 0; k < H; ++k)
        m1 += __shfl(h, k, 64) * w2aT[k * H + f];
    float h2a = fmaxf(m1, 0.f);
    float m2 = b2b[f];
#pragma unroll 16
    for (int k = 0; k < H; ++k)
        m2 += __shfl(h2a, k, 64) * w2bT[k * H + f];
    float h2 = fmaxf(m2, 0.f);
    float accr = br1[fh];
#pragma unroll 16
    for (int k = 0; k < H; ++k)
        accr += __shfl(h2, k, 64) * wr1T[k * 32 + fh];
    float r = fmaxf(accr, 0.f);
    float val = (f < 32) ? r * wr2[fh] : 0.f;
#pragma unroll
    for (int off = 32; off > 0; off >>= 1)
        val += __shfl_xor(val, off, 64);
    if (f == 0) {
        float z = val + br2[0];
        float sig = 1.f / (1.f + expf(-z));
        float p = sig * (1.f - (float)term[n]);
        pi[n] = p;
        atomicAdd(&te[batch[n]], p * ccost[n]);
    }
}

__global__ void final_kernel(const float* __restrict__ pi,
                             const int* __restrict__ batch,
                             const float* __restrict__ Btot,
                             const float* __restrict__ te,
                             float* __restrict__ out) {
    int n = blockIdx.x * blockDim.x + threadIdx.x;
    if (n >= N_NODES) return;
    int b = batch[n];
    float ratio = fminf(Btot[b] / (te[b] + 1e-12f), 1.f);
    out[n] = pi[n] * ratio;
}

extern "C" void kernel_launch(void* const* d_in, const int* in_sizes, int n_in,
                              void* d_out, int out_size, void* d_ws, size_t ws_size,
                              hipStream_t stream) {
    const float* x     = (const float*)d_in[0];
    const int*   ei    = (const int*)d_in[1];
    const float* ea    = (const float*)d_in[2];
    const int*   batch = (const int*)d_in[3];
    const float* Btot  = (const float*)d_in[4];
    const int*   term  = (const int*)d_in[5];
    const float* ccost = (const float*)d_in[6];
    const float* e1w   = (const float*)d_in[7];
    const float* e1b   = (const float*)d_in[8];
    const float* w1a   = (const float*)d_in[9];
    const float* b1a   = (const float*)d_in[10];
    const float* w1b   = (const float*)d_in[11];
    const float* b1b   = (const float*)d_in[12];
    const float* e2w   = (const float*)d_in[13];
    const float* e2b   = (const float*)d_in[14];
    const float* w2a   = (const float*)d_in[15];
    const float* b2a   = (const float*)d_in[16];
    const float* w2b   = (const float*)d_in[17];
    const float* b2b   = (const float*)d_in[18];
    const float* wr1   = (const float*)d_in[19];
    const float* br1   = (const float*)d_in[20];
    const float* wr2   = (const float*)d_in[21];
    const float* br2   = (const float*)d_in[22];

    char* p = (char*)d_ws;
    int*      deg    = (int*)p;      p += sizeof(int)      * N_NODES;   // zeroed
    float*    te     = (float*)p;    p += sizeof(float)    * N_GRAPHS;  // zeroed
    int*      starts = (int*)p;      p += sizeof(int)      * N_NODES;
    int*      next   = (int*)p;      p += sizeof(int)      * N_NODES;
    int*      csum   = (int*)p;      p += sizeof(int)      * 64;
    int*      coff   = (int*)p;      p += sizeof(int)      * 64;
    unsigned* ep4    = (unsigned*)p; p += sizeof(unsigned) * (size_t)N_EDGES;
    __half*   h1lo   = (__half*)p;   p += sizeof(__half)   * (size_t)N_NODES * 32;
    __half*   h1hi   = (__half*)p;   p += sizeof(__half)   * (size_t)N_NODES * 32;
    float*    aggA   = (float*)p;    p += sizeof(float)    * (size_t)N_NODES * 32;
    float*    aggB   = (float*)p;    p += sizeof(float)    * (size_t)N_NODES * 32;
    float*    pi     = (float*)p;    p += sizeof(float)    * N_NODES;
    float*    w1aT   = (float*)p;    p += sizeof(float)    * F_IN * H;
    float*    w1bT   = (float*)p;    p += sizeof(float)    * H * H;
    float*    w2aT   = (float*)p;    p += sizeof(float)    * H * H;
    float*    w2bT   = (float*)p;    p += sizeof(float)    * H * H;
    float*    wr1T   = (float*)p;    p += sizeof(float)    * H * 32;
    float*    out    = (float*)d_out;

    hipMemsetAsync(d_ws, 0, sizeof(int) * N_NODES + sizeof(float) * N_GRAPHS, stream);

    prep_kernel<<<1 + (N_EDGES / 4 + 255) / 256, 256, 0, stream>>>(
        ei, deg, w1a, w1b, w2a, w2b, wr1, w1aT, w1bT, w2aT, w2bT, wr1T);
    scan_local<<<N_CHUNKS, SCAN_BLOCK, 0, stream>>>(deg, starts, csum);
    scan_top<<<1, 64, 0, stream>>>(csum, coff);
    scan_add<<<N_CHUNKS, SCAN_BLOCK, 0, stream>>>(starts, next, coff);
    scatter_kernel<<<(N_EDGES + 255) / 256, 256, 0, stream>>>(ei, ea, next, ep4);
    conv1_kernel<<<(N_NODES + 3) / 4, 256, 0, stream>>>(x, starts, deg, ep4,
                                                        e1w, e1b, w1aT, b1a, w1bT, b1b,
                                                        h1lo, h1hi);
    // temporally-separated phases: each keeps its 3.2MB half L2-resident
    aggphase_kernel<<<(N_NODES + 3) / 4, 256, 0, stream>>>(h1lo, starts, deg, ep4,
                                                           e2w, e2b, aggA);
    aggphase_kernel<<<(N_NODES + 3) / 4, 256, 0, stream>>>(h1hi, starts, deg, ep4,
                                                           e2w + 32, e2b + 32, aggB);
    node2_kernel<<<(N_NODES + 3) / 4, 256, 0, stream>>>(h1lo, h1hi, aggA, aggB,
                                                        w2aT, b2a, w2bT, b2b,
                                                        wr1T, br1, wr2, br2,
                                                        term, ccost, batch, pi, te);
    final_kernel<<<(N_NODES + 255) / 256, 256, 0, stream>>>(pi, batch, Btot, te, out);
}

// Round 11
// 468.023 us; speedup vs baseline: 1.1865x; 1.1865x over previous
//
#include <hip/hip_runtime.h>
#include <hip/hip_fp16.h>
#include <math.h>

#define N_NODES 50000
#define N_EDGES 1600000
#define N_GRAPHS 512
#define F_IN 9
#define H 64
#define SCAN_BLOCK 1024
#define N_CHUNKS ((N_NODES + SCAN_BLOCK - 1) / SCAN_BLOCK)   // 49

typedef _Float16 f16x8 __attribute__((ext_vector_type(8)));
typedef float f32x4 __attribute__((ext_vector_type(4)));

// ---------- prep: block 0 transposes/packs weights (hi/lo split), blocks >=1 histogram ----------
// pk layout for mfma_f32_16x16x32_f16 B-fragment: pk[((t*2+c)*64 + lane)*8 + j]
//   = W[f = t*16 + (lane&15)][k = c*32 + (lane>>4)*8 + j]
__global__ void prep_kernel(const int* __restrict__ ei, int* __restrict__ deg,
                            const float* __restrict__ w1a,
                            const float* __restrict__ w1b,
                            const float* __restrict__ w2a,
                            const float* __restrict__ w2b,
                            const float* __restrict__ wr1,
                            float* __restrict__ w1aT,
                            float* __restrict__ w1bT,
                            __half* __restrict__ pkAh, __half* __restrict__ pkAl,
                            __half* __restrict__ pkBh, __half* __restrict__ pkBl,
                            __half* __restrict__ pkRh, __half* __restrict__ pkRl) {
    if (blockIdx.x == 0) {
        int t = threadIdx.x;
        for (int i = t; i < H * F_IN; i += 256) {
            int f = i / F_IN, k = i % F_IN;
            w1aT[k * H + f] = w1a[i];
        }
        for (int i = t; i < H * H; i += 256) {
            int f = i / H, k = i % H;
            w1bT[k * H + f] = w1b[i];
        }
        for (int i = t; i < 4096; i += 256) {
            int j = i & 7, l = (i >> 3) & 63, c = (i >> 9) & 1, tt = i >> 10;
            int q = l >> 4, n = l & 15;
            int src = (tt * 16 + n) * H + c * 32 + q * 8 + j;
            float wa = w2a[src], wb = w2b[src];
            __half ah = __float2half(wa), bh = __float2half(wb);
            pkAh[i] = ah; pkAl[i] = __float2half(wa - __half2float(ah));
            pkBh[i] = bh; pkBl[i] = __float2half(wb - __half2float(bh));
        }
        for (int i = t; i < 2048; i += 256) {
            int j = i & 7, l = (i >> 3) & 63, c = (i >> 9) & 1, tt = i >> 10;
            int q = l >> 4, n = l & 15;
            float wr = wr1[(tt * 16 + n) * H + c * 32 + q * 8 + j];
            __half rh = __float2half(wr);
            pkRh[i] = rh; pkRl[i] = __float2half(wr - __half2float(rh));
        }
        return;
    }
    int t = (blockIdx.x - 1) * blockDim.x + threadIdx.x;
    if (t >= N_EDGES / 4) return;
    int4 d4 = ((const int4*)(ei + N_EDGES))[t];
    atomicAdd(&deg[d4.x], 1);
    atomicAdd(&deg[d4.y], 1);
    atomicAdd(&deg[d4.z], 1);
    atomicAdd(&deg[d4.w], 1);
}

__global__ void scan_local(const int* __restrict__ deg,
                           int* __restrict__ starts,
                           int* __restrict__ csum) {
    __shared__ int wsum[16];
    __shared__ int woff[16];
    int tid = threadIdx.x, lane = tid & 63, wid = tid >> 6;
    int i = blockIdx.x * SCAN_BLOCK + tid;
    int v = (i < N_NODES) ? deg[i] : 0;
    int incl = v;
#pragma unroll
    for (int off = 1; off < 64; off <<= 1) {
        int t = __shfl_up(incl, off, 64);
        if (lane >= off) incl += t;
    }
    if (lane == 63) wsum[wid] = incl;
    __syncthreads();
    if (wid == 0) {
        int wv = (lane < 16) ? wsum[lane] : 0;
        int winc = wv;
#pragma unroll
        for (int off = 1; off < 16; off <<= 1) {
            int t = __shfl_up(winc, off, 64);
            if (lane >= off) winc += t;
        }
        if (lane < 16) woff[lane] = winc - wv;
    }
    __syncthreads();
    if (i < N_NODES) starts[i] = woff[wid] + (incl - v);
    if (tid == 0) csum[blockIdx.x] = woff[15] + wsum[15];
}

__global__ void scan_top(const int* __restrict__ csum, int* __restrict__ coff) {
    int lane = threadIdx.x;
    int v = (lane < N_CHUNKS) ? csum[lane] : 0;
    int incl = v;
#pragma unroll
    for (int off = 1; off < 64; off <<= 1) {
        int t = __shfl_up(incl, off, 64);
        if (lane >= off) incl += t;
    }
    if (lane < N_CHUNKS) coff[lane] = incl - v;
}

__global__ void scan_add(int* __restrict__ starts, int* __restrict__ next,
                         const int* __restrict__ coff) {
    int i = blockIdx.x * SCAN_BLOCK + threadIdx.x;
    if (i >= N_NODES) return;
    int s = starts[i] + coff[blockIdx.x];
    starts[i] = s;
    next[i] = s;
}

// pack (src:16 | attr:fp16) into 4B
__global__ void scatter_kernel(const int* __restrict__ ei,
                               const float* __restrict__ ea,
                               int* __restrict__ next,
                               unsigned* __restrict__ ep4) {
    int e = blockIdx.x * blockDim.x + threadIdx.x;
    if (e >= N_EDGES) return;
    int d = ei[N_EDGES + e];
    int pos = atomicAdd(&next[d], 1);
    unsigned pv = ((unsigned)ei[e] << 16) |
                  (unsigned)__half_as_ushort(__float2half(ea[e]));
    ep4[pos] = pv;
}

#define UNPACK_ATTR(P) __half2float(__ushort_as_half((unsigned short)((P) & 0xffffu)))

// ---------- conv1 fused: aggregation + MLP; writes feature-split h1 halves ----------
__global__ void conv1_kernel(const float* __restrict__ x,
                             const int* __restrict__ starts,
                             const int* __restrict__ deg,
                             const unsigned* __restrict__ ep4,
                             const float* __restrict__ e1w,
                             const float* __restrict__ e1b,
                             const float* __restrict__ w1aT,
                             const float* __restrict__ b1a,
                             const float* __restrict__ w1bT,
                             const float* __restrict__ b1b,
                             __half* __restrict__ h1lo,
                             __half* __restrict__ h1hi) {
    int n = blockIdx.x * (blockDim.x >> 6) + (threadIdx.x >> 6);
    int lane = threadIdx.x & 63;
    if (n >= N_NODES) return;
    int slot = lane >> 4;
    int f = lane & 15;
    int s0 = starts[n], dg = deg[n];
    bool act = f < F_IN;
    float wf = act ? e1w[f] : 0.f;
    float bf = act ? e1b[f] : 0.f;
    float acc = 0.f;
    int j = slot;
    for (; j + 12 < dg; j += 16) {
        unsigned pa = ep4[s0 + j];
        unsigned pb = ep4[s0 + j + 4];
        unsigned pc = ep4[s0 + j + 8];
        unsigned pd = ep4[s0 + j + 12];
        float xa_ = act ? x[(pa >> 16) * F_IN + f] : 0.f;
        float xb_ = act ? x[(pb >> 16) * F_IN + f] : 0.f;
        float xc_ = act ? x[(pc >> 16) * F_IN + f] : 0.f;
        float xd_ = act ? x[(pd >> 16) * F_IN + f] : 0.f;
        if (act) {
            acc += fmaxf(xa_ + UNPACK_ATTR(pa) * wf + bf, 0.f)
                 + fmaxf(xb_ + UNPACK_ATTR(pb) * wf + bf, 0.f)
                 + fmaxf(xc_ + UNPACK_ATTR(pc) * wf + bf, 0.f)
                 + fmaxf(xd_ + UNPACK_ATTR(pd) * wf + bf, 0.f);
        }
    }
    for (; j < dg; j += 4) {
        unsigned p = ep4[s0 + j];
        float xv = act ? x[(p >> 16) * F_IN + f] : 0.f;
        float m = xv + UNPACK_ATTR(p) * wf + bf;
        acc += act ? fmaxf(m, 0.f) : 0.f;
    }
    acc += __shfl_xor(acc, 16, 64);
    acc += __shfl_xor(acc, 32, 64);
    float xa = (lane < F_IN) ? x[n * F_IN + lane] + acc : 0.f;
    float a1 = b1a[lane];
#pragma unroll
    for (int k = 0; k < F_IN; ++k)
        a1 += __shfl(xa, k, 64) * w1aT[k * H + lane];
    float ha = fmaxf(a1, 0.f);
    float a2 = b1b[lane];
#pragma unroll 16
    for (int k = 0; k < H; ++k)
        a2 += __shfl(ha, k, 64) * w1bT[k * H + lane];
    __half hv = __float2half(fmaxf(a2, 0.f));
    if (lane < 32) h1lo[n * 32 + lane] = hv;
    else           h1hi[n * 32 + (lane - 32)] = hv;
}

// ---------- conv2 aggregation phase (own launch, 3.2MB half stays L2-resident);
// fuses h = h1 + agg and writes FP32 htot[n][64] slice ----------
__global__ void aggphase_kernel(const __half* __restrict__ harr,
                                const int* __restrict__ starts,
                                const int* __restrict__ deg,
                                const unsigned* __restrict__ ep4,
                                const float* __restrict__ ew,
                                const float* __restrict__ eb,
                                float* __restrict__ htot, int foff) {
    int n = blockIdx.x * (blockDim.x >> 6) + (threadIdx.x >> 6);
    int lane = threadIdx.x & 63;
    if (n >= N_NODES) return;
    int half = lane >> 5;
    int fh = lane & 31;
    int s0 = starts[n], dg = deg[n];
    const unsigned* ep = ep4 + s0;
    float wf = ew[fh], bf = eb[fh];
    float acc = 0.f;
    int j = 0;
#define EDGE1(P, V) acc += fmaxf((V) + UNPACK_ATTR(P) * wf + bf, 0.f)
    for (; j + 16 <= dg; j += 16) {
        unsigned p0 = ep[j +  0 + half], p1 = ep[j +  2 + half];
        unsigned p2 = ep[j +  4 + half], p3 = ep[j +  6 + half];
        unsigned p4 = ep[j +  8 + half], p5 = ep[j + 10 + half];
        unsigned p6 = ep[j + 12 + half], p7 = ep[j + 14 + half];
        float v0 = __half2float(harr[(p0 >> 16) * 32 + fh]);
        float v1 = __half2float(harr[(p1 >> 16) * 32 + fh]);
        float v2 = __half2float(harr[(p2 >> 16) * 32 + fh]);
        float v3 = __half2float(harr[(p3 >> 16) * 32 + fh]);
        float v4 = __half2float(harr[(p4 >> 16) * 32 + fh]);
        float v5 = __half2float(harr[(p5 >> 16) * 32 + fh]);
        float v6 = __half2float(harr[(p6 >> 16) * 32 + fh]);
        float v7 = __half2float(harr[(p7 >> 16) * 32 + fh]);
        EDGE1(p0, v0); EDGE1(p1, v1); EDGE1(p2, v2); EDGE1(p3, v3);
        EDGE1(p4, v4); EDGE1(p5, v5); EDGE1(p6, v6); EDGE1(p7, v7);
    }
    for (; j + 2 <= dg; j += 2) {
        unsigned p = ep[j + half];
        float v = __half2float(harr[(p >> 16) * 32 + fh]);
        EDGE1(p, v);
    }
    if (j < dg && half == 0) {
        unsigned p = ep[j];
        float v = __half2float(harr[(p >> 16) * 32 + fh]);
        EDGE1(p, v);
    }
#undef EDGE1
    acc += __shfl_xor(acc, 32, 64);
    if (half == 0) {
        float h1v = __half2float(harr[n * 32 + fh]);
        htot[(size_t)n * 64 + foff + fh] = h1v + acc;
    }
}

// split 8 fp32 values into hi/lo fp16 fragments
__device__ __forceinline__ void split8(const float* __restrict__ v,
                                       f16x8& hi, f16x8& lo) {
#pragma unroll
    for (int j = 0; j < 8; ++j) {
        _Float16 h = (_Float16)v[j];
        hi[j] = h;
        lo[j] = (_Float16)(v[j] - (float)h);
    }
}

// ---------- node2 via split-fp16 MFMA (fp32-grade precision): wave = 16 nodes ----------
__global__ void node2_kernel(const float* __restrict__ htot,
                             const __half* __restrict__ pkAh, const __half* __restrict__ pkAl,
                             const float* __restrict__ b2a,
                             const __half* __restrict__ pkBh, const __half* __restrict__ pkBl,
                             const float* __restrict__ b2b,
                             const __half* __restrict__ pkRh, const __half* __restrict__ pkRl,
                             const float* __restrict__ br1,
                             const float* __restrict__ wr2,
                             const float* __restrict__ br2,
                             const int* __restrict__ term,
                             const float* __restrict__ ccost,
                             const int* __restrict__ batch,
                             float* __restrict__ pi,
                             float* __restrict__ te) {
    __shared__ float hbuf[4][16][68];   // +4 pad: row stride 272B -> 2-way banks (free)
    int wv = threadIdx.x >> 6;
    int lane = threadIdx.x & 63;
    int gwave = blockIdx.x * 4 + wv;
    bool active = gwave < (N_NODES / 16);     // 50000 = 16*3125 exactly
    int base = active ? gwave * 16 : 0;
    int m = lane & 15, q = lane >> 4;
    const _Float16* pAh = (const _Float16*)pkAh;
    const _Float16* pAl = (const _Float16*)pkAl;
    const _Float16* pBh = (const _Float16*)pkBh;
    const _Float16* pBl = (const _Float16*)pkBl;
    const _Float16* pRh = (const _Float16*)pkRh;
    const _Float16* pRl = (const _Float16*)pkRl;

#define TILE3(C, A0H, A0L, A1H, A1L, PH, PL, T) do {                          \
        f16x8 b0h = *(const f16x8*)((PH) + (((T) * 2 + 0) * 64 + lane) * 8);  \
        f16x8 b0l = *(const f16x8*)((PL) + (((T) * 2 + 0) * 64 + lane) * 8);  \
        f16x8 b1h = *(const f16x8*)((PH) + (((T) * 2 + 1) * 64 + lane) * 8);  \
        f16x8 b1l = *(const f16x8*)((PL) + (((T) * 2 + 1) * 64 + lane) * 8);  \
        C = __builtin_amdgcn_mfma_f32_16x16x32_f16(A0H, b0h, C, 0, 0, 0);     \
        C = __builtin_amdgcn_mfma_f32_16x16x32_f16(A0L, b0h, C, 0, 0, 0);     \
        C = __builtin_amdgcn_mfma_f32_16x16x32_f16(A0H, b0l, C, 0, 0, 0);     \
        C = __builtin_amdgcn_mfma_f32_16x16x32_f16(A1H, b1h, C, 0, 0, 0);     \
        C = __builtin_amdgcn_mfma_f32_16x16x32_f16(A1L, b1h, C, 0, 0, 0);     \
        C = __builtin_amdgcn_mfma_f32_16x16x32_f16(A1H, b1l, C, 0, 0, 0);     \
    } while (0)

    // layer 1: A from global fp32 htot, split into hi/lo
    f16x8 a0h, a0l, a1h, a1l;
    {
        const float* hrow = htot + (size_t)(base + m) * 64;
        split8(hrow + q * 8, a0h, a0l);
        split8(hrow + 32 + q * 8, a1h, a1l);
    }
#pragma unroll
    for (int t = 0; t < 4; ++t) {
        f32x4 c = {0.f, 0.f, 0.f, 0.f};
        TILE3(c, a0h, a0l, a1h, a1l, pAh, pAl, t);
        float bias = b2a[t * 16 + m];
#pragma unroll
        for (int r = 0; r < 4; ++r)    // C: col=lane&15 (feat), row=q*4+r (node)
            hbuf[wv][q * 4 + r][t * 16 + m] = fmaxf(c[r] + bias, 0.f);
    }
    __syncthreads();
    // layer 2
    split8(&hbuf[wv][m][q * 8], a0h, a0l);
    split8(&hbuf[wv][m][32 + q * 8], a1h, a1l);
    float tmp[4][4];
#pragma unroll
    for (int t = 0; t < 4; ++t) {
        f32x4 c = {0.f, 0.f, 0.f, 0.f};
        TILE3(c, a0h, a0l, a1h, a1l, pBh, pBl, t);
        float bias = b2b[t * 16 + m];
#pragma unroll
        for (int r = 0; r < 4; ++r)
            tmp[t][r] = fmaxf(c[r] + bias, 0.f);
    }
    __syncthreads();
#pragma unroll
    for (int t = 0; t < 4; ++t)
#pragma unroll
        for (int r = 0; r < 4; ++r)
            hbuf[wv][q * 4 + r][t * 16 + m] = tmp[t][r];
    __syncthreads();
    // layer 3: readout1 (64 -> 32) + dot with wr2
    split8(&hbuf[wv][m][q * 8], a0h, a0l);
    split8(&hbuf[wv][m][32 + q * 8], a1h, a1l);
    float partial[4] = {0.f, 0.f, 0.f, 0.f};
#pragma unroll
    for (int t = 0; t < 2; ++t) {
        f32x4 c = {0.f, 0.f, 0.f, 0.f};
        TILE3(c, a0h, a0l, a1h, a1l, pRh, pRl, t);
        float bias = br1[t * 16 + m];
        float wv2 = wr2[t * 16 + m];
#pragma unroll
        for (int r = 0; r < 4; ++r)
            partial[r] += fmaxf(c[r] + bias, 0.f) * wv2;
    }
#undef TILE3
    // reduce across the 16 lanes sharing q (m = 0..15)
#pragma unroll
    for (int off = 1; off < 16; off <<= 1) {
        partial[0] += __shfl_xor(partial[0], off, 64);
        partial[1] += __shfl_xor(partial[1], off, 64);
        partial[2] += __shfl_xor(partial[2], off, 64);
        partial[3] += __shfl_xor(partial[3], off, 64);
    }
    if (active && m == 0) {
#pragma unroll
        for (int r = 0; r < 4; ++r) {
            int n = base + q * 4 + r;
            float z = partial[r] + br2[0];
            float sig = 1.f / (1.f + expf(-z));
            float p = sig * (1.f - (float)term[n]);
            pi[n] = p;
            atomicAdd(&te[batch[n]], p * ccost[n]);
        }
    }
}

__global__ void final_kernel(const float* __restrict__ pi,
                             const int* __restrict__ batch,
                             const float* __restrict__ Btot,
                             const float* __restrict__ te,
                             float* __restrict__ out) {
    int n = blockIdx.x * blockDim.x + threadIdx.x;
    if (n >= N_NODES) return;
    int b = batch[n];
    float ratio = fminf(Btot[b] / (te[b] + 1e-12f), 1.f);
    out[n] = pi[n] * ratio;
}

extern "C" void kernel_launch(void* const* d_in, const int* in_sizes, int n_in,
                              void* d_out, int out_size, void* d_ws, size_t ws_size,
                              hipStream_t stream) {
    const float* x     = (const float*)d_in[0];
    const int*   ei    = (const int*)d_in[1];
    const float* ea    = (const float*)d_in[2];
    const int*   batch = (const int*)d_in[3];
    const float* Btot  = (const float*)d_in[4];
    const int*   term  = (const int*)d_in[5];
    const float* ccost = (const float*)d_in[6];
    const float* e1w   = (const float*)d_in[7];
    const float* e1b   = (const float*)d_in[8];
    const float* w1a   = (const float*)d_in[9];
    const float* b1a   = (const float*)d_in[10];
    const float* w1b   = (const float*)d_in[11];
    const float* b1b   = (const float*)d_in[12];
    const float* e2w   = (const float*)d_in[13];
    const float* e2b   = (const float*)d_in[14];
    const float* w2a   = (const float*)d_in[15];
    const float* b2a   = (const float*)d_in[16];
    const float* w2b   = (const float*)d_in[17];
    const float* b2b   = (const float*)d_in[18];
    const float* wr1   = (const float*)d_in[19];
    const float* br1   = (const float*)d_in[20];
    const float* wr2   = (const float*)d_in[21];
    const float* br2   = (const float*)d_in[22];

    char* p = (char*)d_ws;
    int*      deg    = (int*)p;      p += sizeof(int)      * N_NODES;   // zeroed
    float*    te     = (float*)p;    p += sizeof(float)    * N_GRAPHS;  // zeroed
    int*      starts = (int*)p;      p += sizeof(int)      * N_NODES;
    int*      next   = (int*)p;      p += sizeof(int)      * N_NODES;
    int*      csum   = (int*)p;      p += sizeof(int)      * 64;
    int*      coff   = (int*)p;      p += sizeof(int)      * 64;
    unsigned* ep4    = (unsigned*)p; p += sizeof(unsigned) * (size_t)N_EDGES;
    __half*   h1lo   = (__half*)p;   p += sizeof(__half)   * (size_t)N_NODES * 32;
    __half*   h1hi   = (__half*)p;   p += sizeof(__half)   * (size_t)N_NODES * 32;
    float*    htot   = (float*)p;    p += sizeof(float)    * (size_t)N_NODES * 64;
    float*    pi     = (float*)p;    p += sizeof(float)    * N_NODES;
    float*    w1aT   = (float*)p;    p += sizeof(float)    * F_IN * H;
    float*    w1bT   = (float*)p;    p += sizeof(float)    * H * H;
    __half*   pkAh   = (__half*)p;   p += sizeof(__half)   * 4096;
    __half*   pkAl   = (__half*)p;   p += sizeof(__half)   * 4096;
    __half*   pkBh   = (__half*)p;   p += sizeof(__half)   * 4096;
    __half*   pkBl   = (__half*)p;   p += sizeof(__half)   * 4096;
    __half*   pkRh   = (__half*)p;   p += sizeof(__half)   * 2048;
    __half*   pkRl   = (__half*)p;   p += sizeof(__half)   * 2048;
    float*    out    = (float*)d_out;

    hipMemsetAsync(d_ws, 0, sizeof(int) * N_NODES + sizeof(float) * N_GRAPHS, stream);

    prep_kernel<<<1 + (N_EDGES / 4 + 255) / 256, 256, 0, stream>>>(
        ei, deg, w1a, w1b, w2a, w2b, wr1, w1aT, w1bT,
        pkAh, pkAl, pkBh, pkBl, pkRh, pkRl);
    scan_local<<<N_CHUNKS, SCAN_BLOCK, 0, stream>>>(deg, starts, csum);
    scan_top<<<1, 64, 0, stream>>>(csum, coff);
    scan_add<<<N_CHUNKS, SCAN_BLOCK, 0, stream>>>(starts, next, coff);
    scatter_kernel<<<(N_EDGES + 255) / 256, 256, 0, stream>>>(ei, ea, next, ep4);
    conv1_kernel<<<(N_NODES + 3) / 4, 256, 0, stream>>>(x, starts, deg, ep4,
                                                        e1w, e1b, w1aT, b1a, w1bT, b1b,
                                                        h1lo, h1hi);
    aggphase_kernel<<<(N_NODES + 3) / 4, 256, 0, stream>>>(h1lo, starts, deg, ep4,
                                                           e2w, e2b, htot, 0);
    aggphase_kernel<<<(N_NODES + 3) / 4, 256, 0, stream>>>(h1hi, starts, deg, ep4,
                                                           e2w + 32, e2b + 32, htot, 32);
    node2_kernel<<<(N_NODES / 16 + 3) / 4, 256, 0, stream>>>(htot,
                                                             pkAh, pkAl, b2a,
                                                             pkBh, pkBl, b2b,
                                                             pkRh, pkRl, br1,
                                                             wr2, br2,
                                                             term, ccost, batch, pi, te);
    final_kernel<<<(N_NODES + 255) / 256, 256, 0, stream>>>(pi, batch, Btot, te, out);
}

// Round 12
// 441.110 us; speedup vs baseline: 1.2589x; 1.0610x over previous
//
#include <hip/hip_runtime.h>
#include <hip/hip_fp16.h>
#include <math.h>

#define N_NODES 50000
#define N_EDGES 1600000
#define N_GRAPHS 512
#define F_IN 9
#define H 64
#define SCAN_BLOCK 1024
#define N_CHUNKS ((N_NODES + SCAN_BLOCK - 1) / SCAN_BLOCK)   // 49
#define N_SEG 8
#define SEG_SIZE ((N_NODES + N_SEG - 1) / N_SEG)             // 6250
#define EDGES_PER_BLOCK 1024
#define N_ECHUNK ((N_EDGES + EDGES_PER_BLOCK - 1) / EDGES_PER_BLOCK)  // 1563

typedef _Float16 f16x8 __attribute__((ext_vector_type(8)));
typedef float f32x4 __attribute__((ext_vector_type(4)));

// ---------- weight packing (1 block) ----------
__global__ void pack_weights(const float* __restrict__ w1a,
                             const float* __restrict__ w1b,
                             const float* __restrict__ w2a,
                             const float* __restrict__ w2b,
                             const float* __restrict__ wr1,
                             float* __restrict__ w1aT,
                             float* __restrict__ w1bT,
                             __half* __restrict__ pkAh, __half* __restrict__ pkAl,
                             __half* __restrict__ pkBh, __half* __restrict__ pkBl,
                             __half* __restrict__ pkRh, __half* __restrict__ pkRl) {
    int t = threadIdx.x;
    for (int i = t; i < H * F_IN; i += 256) {
        int f = i / F_IN, k = i % F_IN;
        w1aT[k * H + f] = w1a[i];
    }
    for (int i = t; i < H * H; i += 256) {
        int f = i / H, k = i % H;
        w1bT[k * H + f] = w1b[i];
    }
    for (int i = t; i < 4096; i += 256) {
        int j = i & 7, l = (i >> 3) & 63, c = (i >> 9) & 1, tt = i >> 10;
        int q = l >> 4, n = l & 15;
        int src = (tt * 16 + n) * H + c * 32 + q * 8 + j;
        float wa = w2a[src], wb = w2b[src];
        __half ah = __float2half(wa), bh = __float2half(wb);
        pkAh[i] = ah; pkAl[i] = __float2half(wa - __half2float(ah));
        pkBh[i] = bh; pkBl[i] = __float2half(wb - __half2float(bh));
    }
    for (int i = t; i < 2048; i += 256) {
        int j = i & 7, l = (i >> 3) & 63, c = (i >> 9) & 1, tt = i >> 10;
        int q = l >> 4, n = l & 15;
        float wr = wr1[(tt * 16 + n) * H + c * 32 + q * 8 + j];
        __half rh = __float2half(wr);
        pkRh[i] = rh; pkRl[i] = __float2half(wr - __half2float(rh));
    }
}

// ---------- XCD-partitioned histogram: block b = (chunk b>>3, segment b&7).
// Assuming consecutive blockIdx round-robin across XCDs, segment r's deg lines
// are touched only by XCD r -> no cross-XCD line bouncing. ----------
__global__ void hist_seg(const int* __restrict__ ei, int* __restrict__ deg) {
    int seg = blockIdx.x & 7;
    int chunk = blockIdx.x >> 3;
    int lo = seg * SEG_SIZE, hi = lo + SEG_SIZE;
    int base = chunk * EDGES_PER_BLOCK + threadIdx.x * 4;
    if (base >= N_EDGES) return;
    int4 d4 = *(const int4*)(ei + N_EDGES + base);
    if (d4.x >= lo && d4.x < hi) atomicAdd(&deg[d4.x], 1);
    if (d4.y >= lo && d4.y < hi) atomicAdd(&deg[d4.y], 1);
    if (d4.z >= lo && d4.z < hi) atomicAdd(&deg[d4.z], 1);
    if (d4.w >= lo && d4.w < hi) atomicAdd(&deg[d4.w], 1);
}

__global__ void scan_local(const int* __restrict__ deg,
                           int* __restrict__ starts,
                           int* __restrict__ csum) {
    __shared__ int wsum[16];
    __shared__ int woff[16];
    int tid = threadIdx.x, lane = tid & 63, wid = tid >> 6;
    int i = blockIdx.x * SCAN_BLOCK + tid;
    int v = (i < N_NODES) ? deg[i] : 0;
    int incl = v;
#pragma unroll
    for (int off = 1; off < 64; off <<= 1) {
        int t = __shfl_up(incl, off, 64);
        if (lane >= off) incl += t;
    }
    if (lane == 63) wsum[wid] = incl;
    __syncthreads();
    if (wid == 0) {
        int wv = (lane < 16) ? wsum[lane] : 0;
        int winc = wv;
#pragma unroll
        for (int off = 1; off < 16; off <<= 1) {
            int t = __shfl_up(winc, off, 64);
            if (lane >= off) winc += t;
        }
        if (lane < 16) woff[lane] = winc - wv;
    }
    __syncthreads();
    if (i < N_NODES) starts[i] = woff[wid] + (incl - v);
    if (tid == 0) csum[blockIdx.x] = woff[15] + wsum[15];
}

__global__ void scan_top(const int* __restrict__ csum, int* __restrict__ coff) {
    int lane = threadIdx.x;
    int v = (lane < N_CHUNKS) ? csum[lane] : 0;
    int incl = v;
#pragma unroll
    for (int off = 1; off < 64; off <<= 1) {
        int t = __shfl_up(incl, off, 64);
        if (lane >= off) incl += t;
    }
    if (lane < N_CHUNKS) coff[lane] = incl - v;
}

__global__ void scan_add(int* __restrict__ starts, int* __restrict__ next,
                         const int* __restrict__ coff) {
    int i = blockIdx.x * SCAN_BLOCK + threadIdx.x;
    if (i >= N_NODES) return;
    int s = starts[i] + coff[blockIdx.x];
    starts[i] = s;
    next[i] = s;
}

// ---------- XCD-partitioned scatter: same (chunk, segment) decomposition.
// Writes into ep4 slice for segment r come only from XCD r. ----------
__global__ void scatter_seg(const int* __restrict__ ei,
                            const float* __restrict__ ea,
                            int* __restrict__ next,
                            unsigned* __restrict__ ep4) {
    int seg = blockIdx.x & 7;
    int chunk = blockIdx.x >> 3;
    int lo = seg * SEG_SIZE, hi = lo + SEG_SIZE;
    int base = chunk * EDGES_PER_BLOCK + threadIdx.x * 4;
    if (base >= N_EDGES) return;
    int4 d4 = *(const int4*)(ei + N_EDGES + base);
#define DO_EDGE(D, K) do {                                                  \
        if ((D) >= lo && (D) < hi) {                                        \
            int e = base + (K);                                             \
            int pos = atomicAdd(&next[D], 1);                               \
            ep4[pos] = ((unsigned)ei[e] << 16) |                            \
                       (unsigned)__half_as_ushort(__float2half(ea[e]));     \
        }                                                                   \
    } while (0)
    DO_EDGE(d4.x, 0);
    DO_EDGE(d4.y, 1);
    DO_EDGE(d4.z, 2);
    DO_EDGE(d4.w, 3);
#undef DO_EDGE
}

#define UNPACK_ATTR(P) __half2float(__ushort_as_half((unsigned short)((P) & 0xffffu)))

// ---------- conv1 fused: aggregation + MLP; writes feature-split h1 halves ----------
__global__ void conv1_kernel(const float* __restrict__ x,
                             const int* __restrict__ starts,
                             const int* __restrict__ deg,
                             const unsigned* __restrict__ ep4,
                             const float* __restrict__ e1w,
                             const float* __restrict__ e1b,
                             const float* __restrict__ w1aT,
                             const float* __restrict__ b1a,
                             const float* __restrict__ w1bT,
                             const float* __restrict__ b1b,
                             __half* __restrict__ h1lo,
                             __half* __restrict__ h1hi) {
    int n = blockIdx.x * (blockDim.x >> 6) + (threadIdx.x >> 6);
    int lane = threadIdx.x & 63;
    if (n >= N_NODES) return;
    int slot = lane >> 4;
    int f = lane & 15;
    int s0 = starts[n], dg = deg[n];
    bool act = f < F_IN;
    float wf = act ? e1w[f] : 0.f;
    float bf = act ? e1b[f] : 0.f;
    float acc = 0.f;
    int j = slot;
    for (; j + 12 < dg; j += 16) {
        unsigned pa = ep4[s0 + j];
        unsigned pb = ep4[s0 + j + 4];
        unsigned pc = ep4[s0 + j + 8];
        unsigned pd = ep4[s0 + j + 12];
        float xa_ = act ? x[(pa >> 16) * F_IN + f] : 0.f;
        float xb_ = act ? x[(pb >> 16) * F_IN + f] : 0.f;
        float xc_ = act ? x[(pc >> 16) * F_IN + f] : 0.f;
        float xd_ = act ? x[(pd >> 16) * F_IN + f] : 0.f;
        if (act) {
            acc += fmaxf(xa_ + UNPACK_ATTR(pa) * wf + bf, 0.f)
                 + fmaxf(xb_ + UNPACK_ATTR(pb) * wf + bf, 0.f)
                 + fmaxf(xc_ + UNPACK_ATTR(pc) * wf + bf, 0.f)
                 + fmaxf(xd_ + UNPACK_ATTR(pd) * wf + bf, 0.f);
        }
    }
    for (; j < dg; j += 4) {
        unsigned p = ep4[s0 + j];
        float xv = act ? x[(p >> 16) * F_IN + f] : 0.f;
        float m = xv + UNPACK_ATTR(p) * wf + bf;
        acc += act ? fmaxf(m, 0.f) : 0.f;
    }
    acc += __shfl_xor(acc, 16, 64);
    acc += __shfl_xor(acc, 32, 64);
    float xa = (lane < F_IN) ? x[n * F_IN + lane] + acc : 0.f;
    float a1 = b1a[lane];
#pragma unroll
    for (int k = 0; k < F_IN; ++k)
        a1 += __shfl(xa, k, 64) * w1aT[k * H + lane];
    float ha = fmaxf(a1, 0.f);
    float a2 = b1b[lane];
#pragma unroll 16
    for (int k = 0; k < H; ++k)
        a2 += __shfl(ha, k, 64) * w1bT[k * H + lane];
    __half hv = __float2half(fmaxf(a2, 0.f));
    if (lane < 32) h1lo[n * 32 + lane] = hv;
    else           h1hi[n * 32 + (lane - 32)] = hv;
}

// ---------- conv2 aggregation phase (own launch, 3.2MB half stays L2-resident);
// fuses h = h1 + agg and writes FP32 htot[n][64] slice ----------
__global__ void aggphase_kernel(const __half* __restrict__ harr,
                                const int* __restrict__ starts,
                                const int* __restrict__ deg,
                                const unsigned* __restrict__ ep4,
                                const float* __restrict__ ew,
                                const float* __restrict__ eb,
                                float* __restrict__ htot, int foff) {
    int n = blockIdx.x * (blockDim.x >> 6) + (threadIdx.x >> 6);
    int lane = threadIdx.x & 63;
    if (n >= N_NODES) return;
    int half = lane >> 5;
    int fh = lane & 31;
    int s0 = starts[n], dg = deg[n];
    const unsigned* ep = ep4 + s0;
    float wf = ew[fh], bf = eb[fh];
    float acc = 0.f;
    int j = 0;
#define EDGE1(P, V) acc += fmaxf((V) + UNPACK_ATTR(P) * wf + bf, 0.f)
    for (; j + 16 <= dg; j += 16) {
        unsigned p0 = ep[j +  0 + half], p1 = ep[j +  2 + half];
        unsigned p2 = ep[j +  4 + half], p3 = ep[j +  6 + half];
        unsigned p4 = ep[j +  8 + half], p5 = ep[j + 10 + half];
        unsigned p6 = ep[j + 12 + half], p7 = ep[j + 14 + half];
        float v0 = __half2float(harr[(p0 >> 16) * 32 + fh]);
        float v1 = __half2float(harr[(p1 >> 16) * 32 + fh]);
        float v2 = __half2float(harr[(p2 >> 16) * 32 + fh]);
        float v3 = __half2float(harr[(p3 >> 16) * 32 + fh]);
        float v4 = __half2float(harr[(p4 >> 16) * 32 + fh]);
        float v5 = __half2float(harr[(p5 >> 16) * 32 + fh]);
        float v6 = __half2float(harr[(p6 >> 16) * 32 + fh]);
        float v7 = __half2float(harr[(p7 >> 16) * 32 + fh]);
        EDGE1(p0, v0); EDGE1(p1, v1); EDGE1(p2, v2); EDGE1(p3, v3);
        EDGE1(p4, v4); EDGE1(p5, v5); EDGE1(p6, v6); EDGE1(p7, v7);
    }
    for (; j + 2 <= dg; j += 2) {
        unsigned p = ep[j + half];
        float v = __half2float(harr[(p >> 16) * 32 + fh]);
        EDGE1(p, v);
    }
    if (j < dg && half == 0) {
        unsigned p = ep[j];
        float v = __half2float(harr[(p >> 16) * 32 + fh]);
        EDGE1(p, v);
    }
#undef EDGE1
    acc += __shfl_xor(acc, 32, 64);
    if (half == 0) {
        float h1v = __half2float(harr[n * 32 + fh]);
        htot[(size_t)n * 64 + foff + fh] = h1v + acc;
    }
}

// split 8 fp32 values into hi/lo fp16 fragments
__device__ __forceinline__ void split8(const float* __restrict__ v,
                                       f16x8& hi, f16x8& lo) {
#pragma unroll
    for (int j = 0; j < 8; ++j) {
        _Float16 h = (_Float16)v[j];
        hi[j] = h;
        lo[j] = (_Float16)(v[j] - (float)h);
    }
}

// ---------- node2 via split-fp16 MFMA (fp32-grade precision): wave = 16 nodes ----------
__global__ void node2_kernel(const float* __restrict__ htot,
                             const __half* __restrict__ pkAh, const __half* __restrict__ pkAl,
                             const float* __restrict__ b2a,
                             const __half* __restrict__ pkBh, const __half* __restrict__ pkBl,
                             const float* __restrict__ b2b,
                             const __half* __restrict__ pkRh, const __half* __restrict__ pkRl,
                             const float* __restrict__ br1,
                             const float* __restrict__ wr2,
                             const float* __restrict__ br2,
                             const int* __restrict__ term,
                             const float* __restrict__ ccost,
                             const int* __restrict__ batch,
                             float* __restrict__ pi,
                             float* __restrict__ te) {
    __shared__ float hbuf[4][16][68];
    int wv = threadIdx.x >> 6;
    int lane = threadIdx.x & 63;
    int gwave = blockIdx.x * 4 + wv;
    bool active = gwave < (N_NODES / 16);     // 50000 = 16*3125 exactly
    int base = active ? gwave * 16 : 0;
    int m = lane & 15, q = lane >> 4;
    const _Float16* pAh = (const _Float16*)pkAh;
    const _Float16* pAl = (const _Float16*)pkAl;
    const _Float16* pBh = (const _Float16*)pkBh;
    const _Float16* pBl = (const _Float16*)pkBl;
    const _Float16* pRh = (const _Float16*)pkRh;
    const _Float16* pRl = (const _Float16*)pkRl;

#define TILE3(C, A0H, A0L, A1H, A1L, PH, PL, T) do {                          \
        f16x8 b0h = *(const f16x8*)((PH) + (((T) * 2 + 0) * 64 + lane) * 8);  \
        f16x8 b0l = *(const f16x8*)((PL) + (((T) * 2 + 0) * 64 + lane) * 8);  \
        f16x8 b1h = *(const f16x8*)((PH) + (((T) * 2 + 1) * 64 + lane) * 8);  \
        f16x8 b1l = *(const f16x8*)((PL) + (((T) * 2 + 1) * 64 + lane) * 8);  \
        C = __builtin_amdgcn_mfma_f32_16x16x32_f16(A0H, b0h, C, 0, 0, 0);     \
        C = __builtin_amdgcn_mfma_f32_16x16x32_f16(A0L, b0h, C, 0, 0, 0);     \
        C = __builtin_amdgcn_mfma_f32_16x16x32_f16(A0H, b0l, C, 0, 0, 0);     \
        C = __builtin_amdgcn_mfma_f32_16x16x32_f16(A1H, b1h, C, 0, 0, 0);     \
        C = __builtin_amdgcn_mfma_f32_16x16x32_f16(A1L, b1h, C, 0, 0, 0);     \
        C = __builtin_amdgcn_mfma_f32_16x16x32_f16(A1H, b1l, C, 0, 0, 0);     \
    } while (0)

    f16x8 a0h, a0l, a1h, a1l;
    {
        const float* hrow = htot + (size_t)(base + m) * 64;
        split8(hrow + q * 8, a0h, a0l);
        split8(hrow + 32 + q * 8, a1h, a1l);
    }
#pragma unroll
    for (int t = 0; t < 4; ++t) {
        f32x4 c = {0.f, 0.f, 0.f, 0.f};
        TILE3(c, a0h, a0l, a1h, a1l, pAh, pAl, t);
        float bias = b2a[t * 16 + m];
#pragma unroll
        for (int r = 0; r < 4; ++r)
            hbuf[wv][q * 4 + r][t * 16 + m] = fmaxf(c[r] + bias, 0.f);
    }
    __syncthreads();
    split8(&hbuf[wv][m][q * 8], a0h, a0l);
    split8(&hbuf[wv][m][32 + q * 8], a1h, a1l);
    float tmp[4][4];
#pragma unroll
    for (int t = 0; t < 4; ++t) {
        f32x4 c = {0.f, 0.f, 0.f, 0.f};
        TILE3(c, a0h, a0l, a1h, a1l, pBh, pBl, t);
        float bias = b2b[t * 16 + m];
#pragma unroll
        for (int r = 0; r < 4; ++r)
            tmp[t][r] = fmaxf(c[r] + bias, 0.f);
    }
    __syncthreads();
#pragma unroll
    for (int t = 0; t < 4; ++t)
#pragma unroll
        for (int r = 0; r < 4; ++r)
            hbuf[wv][q * 4 + r][t * 16 + m] = tmp[t][r];
    __syncthreads();
    split8(&hbuf[wv][m][q * 8], a0h, a0l);
    split8(&hbuf[wv][m][32 + q * 8], a1h, a1l);
    float partial[4] = {0.f, 0.f, 0.f, 0.f};
#pragma unroll
    for (int t = 0; t < 2; ++t) {
        f32x4 c = {0.f, 0.f, 0.f, 0.f};
        TILE3(c, a0h, a0l, a1h, a1l, pRh, pRl, t);
        float bias = br1[t * 16 + m];
        float wv2 = wr2[t * 16 + m];
#pragma unroll
        for (int r = 0; r < 4; ++r)
            partial[r] += fmaxf(c[r] + bias, 0.f) * wv2;
    }
#undef TILE3
#pragma unroll
    for (int off = 1; off < 16; off <<= 1) {
        partial[0] += __shfl_xor(partial[0], off, 64);
        partial[1] += __shfl_xor(partial[1], off, 64);
        partial[2] += __shfl_xor(partial[2], off, 64);
        partial[3] += __shfl_xor(partial[3], off, 64);
    }
    if (active && m == 0) {
#pragma unroll
        for (int r = 0; r < 4; ++r) {
            int n = base + q * 4 + r;
            float z = partial[r] + br2[0];
            float sig = 1.f / (1.f + expf(-z));
            float p = sig * (1.f - (float)term[n]);
            pi[n] = p;
            atomicAdd(&te[batch[n]], p * ccost[n]);
        }
    }
}

__global__ void final_kernel(const float* __restrict__ pi,
                             const int* __restrict__ batch,
                             const float* __restrict__ Btot,
                             const float* __restrict__ te,
                             float* __restrict__ out) {
    int n = blockIdx.x * blockDim.x + threadIdx.x;
    if (n >= N_NODES) return;
    int b = batch[n];
    float ratio = fminf(Btot[b] / (te[b] + 1e-12f), 1.f);
    out[n] = pi[n] * ratio;
}

extern "C" void kernel_launch(void* const* d_in, const int* in_sizes, int n_in,
                              void* d_out, int out_size, void* d_ws, size_t ws_size,
                              hipStream_t stream) {
    const float* x     = (const float*)d_in[0];
    const int*   ei    = (const int*)d_in[1];
    const float* ea    = (const float*)d_in[2];
    const int*   batch = (const int*)d_in[3];
    const float* Btot  = (const float*)d_in[4];
    const int*   term  = (const int*)d_in[5];
    const float* ccost = (const float*)d_in[6];
    const float* e1w   = (const float*)d_in[7];
    const float* e1b   = (const float*)d_in[8];
    const float* w1a   = (const float*)d_in[9];
    const float* b1a   = (const float*)d_in[10];
    const float* w1b   = (const float*)d_in[11];
    const float* b1b   = (const float*)d_in[12];
    const float* e2w   = (const float*)d_in[13];
    const float* e2b   = (const float*)d_in[14];
    const float* w2a   = (const float*)d_in[15];
    const float* b2a   = (const float*)d_in[16];
    const float* w2b   = (const float*)d_in[17];
    const float* b2b   = (const float*)d_in[18];
    const float* wr1   = (const float*)d_in[19];
    const float* br1   = (const float*)d_in[20];
    const float* wr2   = (const float*)d_in[21];
    const float* br2   = (const float*)d_in[22];

    char* p = (char*)d_ws;
    int*      deg    = (int*)p;      p += sizeof(int)      * N_NODES;   // zeroed
    float*    te     = (float*)p;    p += sizeof(float)    * N_GRAPHS;  // zeroed
    int*      starts = (int*)p;      p += sizeof(int)      * N_NODES;
    int*      next   = (int*)p;      p += sizeof(int)      * N_NODES;
    int*      csum   = (int*)p;      p += sizeof(int)      * 64;
    int*      coff   = (int*)p;      p += sizeof(int)      * 64;
    unsigned* ep4    = (unsigned*)p; p += sizeof(unsigned) * (size_t)N_EDGES;
    __half*   h1lo   = (__half*)p;   p += sizeof(__half)   * (size_t)N_NODES * 32;
    __half*   h1hi   = (__half*)p;   p += sizeof(__half)   * (size_t)N_NODES * 32;
    float*    htot   = (float*)p;    p += sizeof(float)    * (size_t)N_NODES * 64;
    float*    pi     = (float*)p;    p += sizeof(float)    * N_NODES;
    float*    w1aT   = (float*)p;    p += sizeof(float)    * F_IN * H;
    float*    w1bT   = (float*)p;    p += sizeof(float)    * H * H;
    __half*   pkAh   = (__half*)p;   p += sizeof(__half)   * 4096;
    __half*   pkAl   = (__half*)p;   p += sizeof(__half)   * 4096;
    __half*   pkBh   = (__half*)p;   p += sizeof(__half)   * 4096;
    __half*   pkBl   = (__half*)p;   p += sizeof(__half)   * 4096;
    __half*   pkRh   = (__half*)p;   p += sizeof(__half)   * 2048;
    __half*   pkRl   = (__half*)p;   p += sizeof(__half)   * 2048;
    float*    out    = (float*)d_out;

    hipMemsetAsync(d_ws, 0, sizeof(int) * N_NODES + sizeof(float) * N_GRAPHS, stream);

    pack_weights<<<1, 256, 0, stream>>>(w1a, w1b, w2a, w2b, wr1, w1aT, w1bT,
                                        pkAh, pkAl, pkBh, pkBl, pkRh, pkRl);
    hist_seg<<<N_ECHUNK * N_SEG, 256, 0, stream>>>(ei, deg);
    scan_local<<<N_CHUNKS, SCAN_BLOCK, 0, stream>>>(deg, starts, csum);
    scan_top<<<1, 64, 0, stream>>>(csum, coff);
    scan_add<<<N_CHUNKS, SCAN_BLOCK, 0, stream>>>(starts, next, coff);
    scatter_seg<<<N_ECHUNK * N_SEG, 256, 0, stream>>>(ei, ea, next, ep4);
    conv1_kernel<<<(N_NODES + 3) / 4, 256, 0, stream>>>(x, starts, deg, ep4,
                                                        e1w, e1b, w1aT, b1a, w1bT, b1b,
                                                        h1lo, h1hi);
    aggphase_kernel<<<(N_NODES + 3) / 4, 256, 0, stream>>>(h1lo, starts, deg, ep4,
                                                           e2w, e2b, htot, 0);
    aggphase_kernel<<<(N_NODES + 3) / 4, 256, 0, stream>>>(h1hi, starts, deg, ep4,
                                                           e2w + 32, e2b + 32, htot, 32);
    node2_kernel<<<(N_NODES / 16 + 3) / 4, 256, 0, stream>>>(htot,
                                                             pkAh, pkAl, b2a,
                                                             pkBh, pkBl, b2b,
                                                             pkRh, pkRl, br1,
                                                             wr2, br2,
                                                             term, ccost, batch, pi, te);
    final_kernel<<<(N_NODES + 255) / 256, 256, 0, stream>>>(pi, batch, Btot, te, out);
}

// Round 13
// 365.166 us; speedup vs baseline: 1.5207x; 1.2080x over previous
//
#include <hip/hip_runtime.h>
#include <hip/hip_fp16.h>
#include <math.h>

#define N_NODES 50000
#define N_EDGES 1600000
#define N_GRAPHS 512
#define F_IN 9
#define H 64
#define N_BUCKETS ((N_NODES + 255) >> 8)     // 196 (bucket = dst >> 8)
#define EPB 8192                              // edges per scatter block
#define N_SBLK ((N_EDGES + EPB - 1) / EPB)    // 196
#define FINE_CAP 10240                        // >> mean 8163 + 20 sd; stat-safe

typedef _Float16 f16x8 __attribute__((ext_vector_type(8)));
typedef float f32x4 __attribute__((ext_vector_type(4)));

// ---------- weight packing (1 block) ----------
__global__ void pack_weights(const float* __restrict__ w1a,
                             const float* __restrict__ w1b,
                             const float* __restrict__ w2a,
                             const float* __restrict__ w2b,
                             const float* __restrict__ wr1,
                             float* __restrict__ w1aT,
                             float* __restrict__ w1bT,
                             __half* __restrict__ pkAh, __half* __restrict__ pkAl,
                             __half* __restrict__ pkBh, __half* __restrict__ pkBl,
                             __half* __restrict__ pkRh, __half* __restrict__ pkRl) {
    int t = threadIdx.x;
    for (int i = t; i < H * F_IN; i += 256) {
        int f = i / F_IN, k = i % F_IN;
        w1aT[k * H + f] = w1a[i];
    }
    for (int i = t; i < H * H; i += 256) {
        int f = i / H, k = i % H;
        w1bT[k * H + f] = w1b[i];
    }
    for (int i = t; i < 4096; i += 256) {
        int j = i & 7, l = (i >> 3) & 63, c = (i >> 9) & 1, tt = i >> 10;
        int q = l >> 4, n = l & 15;
        int src = (tt * 16 + n) * H + c * 32 + q * 8 + j;
        float wa = w2a[src], wb = w2b[src];
        __half ah = __float2half(wa), bh = __float2half(wb);
        pkAh[i] = ah; pkAl[i] = __float2half(wa - __half2float(ah));
        pkBh[i] = bh; pkBl[i] = __float2half(wb - __half2float(bh));
    }
    for (int i = t; i < 2048; i += 256) {
        int j = i & 7, l = (i >> 3) & 63, c = (i >> 9) & 1, tt = i >> 10;
        int q = l >> 4, n = l & 15;
        float wr = wr1[(tt * 16 + n) * H + c * 32 + q * 8 + j];
        __half rh = __float2half(wr);
        pkRh[i] = rh; pkRl[i] = __float2half(wr - __half2float(rh));
    }
}

// ---------- bucket histogram: 196 buckets, LDS-aggregated ----------
__global__ void bucket_hist(const int* __restrict__ ei, int* __restrict__ bcnt) {
    __shared__ int h[N_BUCKETS];
    for (int i = threadIdx.x; i < N_BUCKETS; i += 256) h[i] = 0;
    __syncthreads();
    int t = blockIdx.x * 256 + threadIdx.x;
    if (t < N_EDGES / 4) {
        int4 d4 = ((const int4*)(ei + N_EDGES))[t];
        atomicAdd(&h[d4.x >> 8], 1);
        atomicAdd(&h[d4.y >> 8], 1);
        atomicAdd(&h[d4.z >> 8], 1);
        atomicAdd(&h[d4.w >> 8], 1);
    }
    __syncthreads();
    for (int i = threadIdx.x; i < N_BUCKETS; i += 256)
        if (h[i]) atomicAdd(&bcnt[i], h[i]);
}

// ---------- exclusive scan of 196 bucket counts (1 block) ----------
__global__ void bucket_scan(const int* __restrict__ bcnt,
                            int* __restrict__ bbase, int* __restrict__ bnext) {
    __shared__ int wsum[4];
    int tid = threadIdx.x, lane = tid & 63, wid = tid >> 6;
    int v = (tid < N_BUCKETS) ? bcnt[tid] : 0;
    int incl = v;
#pragma unroll
    for (int off = 1; off < 64; off <<= 1) {
        int t = __shfl_up(incl, off, 64);
        if (lane >= off) incl += t;
    }
    if (lane == 63) wsum[wid] = incl;
    __syncthreads();
    int off = 0;
    for (int w = 0; w < wid; ++w) off += wsum[w];
    int excl = off + incl - v;
    if (tid < N_BUCKETS) { bbase[tid] = excl; bnext[tid] = excl; }
}

// ---------- bucket scatter: block claims a contiguous chunk per bucket
// (one global atomic / bucket / block) -> writes are dense runs ----------
__global__ void bucket_scatter(const int* __restrict__ ei,
                               const float* __restrict__ ea,
                               int* __restrict__ bnext,
                               uint2* __restrict__ ebuk) {
    __shared__ int cnt[N_BUCKETS];
    __shared__ int gbase[N_BUCKETS];
    for (int i = threadIdx.x; i < N_BUCKETS; i += 256) cnt[i] = 0;
    __syncthreads();
    int base = blockIdx.x * EPB;
    int rk[32];   // (b<<21)|(dlocal<<13)|rank ; -1 = inactive
#pragma unroll
    for (int j = 0; j < 32; ++j) {
        int e = base + j * 256 + threadIdx.x;
        rk[j] = -1;
        if (e < N_EDGES) {
            int d = ei[N_EDGES + e];
            int b = d >> 8;
            int r = atomicAdd(&cnt[b], 1);
            rk[j] = (b << 21) | ((d & 255) << 13) | r;
        }
    }
    __syncthreads();
    for (int i = threadIdx.x; i < N_BUCKETS; i += 256)
        gbase[i] = cnt[i] ? atomicAdd(&bnext[i], cnt[i]) : 0;
    __syncthreads();
#pragma unroll
    for (int j = 0; j < 32; ++j) {
        if (rk[j] < 0) continue;
        int e = base + j * 256 + threadIdx.x;
        int b = rk[j] >> 21, dl = (rk[j] >> 13) & 255, r = rk[j] & 8191;
        unsigned pay = ((unsigned)ei[e] << 16) |
                       (unsigned)__half_as_ushort(__float2half(ea[e]));
        ebuk[gbase[b] + r] = make_uint2(pay, (unsigned)dl);
    }
}

// ---------- per-bucket fine sort: node-level CSR (starts/deg) + node-sorted
// ep4, with fully-coalesced global writes ----------
__global__ void __launch_bounds__(256)
bucket_fine(const uint2* __restrict__ ebuk,
            const int* __restrict__ bbase, const int* __restrict__ bcnt,
            unsigned* __restrict__ ep4,
            int* __restrict__ starts, int* __restrict__ deg) {
    __shared__ unsigned sorted[FINE_CAP];
    __shared__ int cntN[256], offN[256], nxtN[256];
    __shared__ int wsum[4];
    int b = blockIdx.x;
    int base = bbase[b];
    int count = bcnt[b];
    if (count > FINE_CAP) count = FINE_CAP;   // statistically unreachable
    int tid = threadIdx.x;
    cntN[tid] = 0;
    __syncthreads();
    for (int i = tid; i < count; i += 256)
        atomicAdd(&cntN[ebuk[base + i].y], 1);
    __syncthreads();
    // block scan of cntN
    int lane = tid & 63, wid = tid >> 6;
    int v = cntN[tid], incl = v;
#pragma unroll
    for (int off = 1; off < 64; off <<= 1) {
        int t = __shfl_up(incl, off, 64);
        if (lane >= off) incl += t;
    }
    if (lane == 63) wsum[wid] = incl;
    __syncthreads();
    int woff = 0;
    for (int w = 0; w < wid; ++w) woff += wsum[w];
    int excl = woff + incl - v;
    offN[tid] = excl;
    nxtN[tid] = 0;
    int n = (b << 8) + tid;
    if (n < N_NODES) { starts[n] = base + excl; deg[n] = v; }
    __syncthreads();
    for (int i = tid; i < count; i += 256) {
        uint2 e = ebuk[base + i];
        int r = atomicAdd(&nxtN[e.y], 1);
        sorted[offN[e.y] + r] = e.x;
    }
    __syncthreads();
    for (int i = tid; i < count; i += 256)
        ep4[base + i] = sorted[i];
}

#define UNPACK_ATTR(P) __half2float(__ushort_as_half((unsigned short)((P) & 0xffffu)))

// ---------- conv1 fused: aggregation + MLP; writes feature-split h1 halves ----------
__global__ void conv1_kernel(const float* __restrict__ x,
                             const int* __restrict__ starts,
                             const int* __restrict__ deg,
                             const unsigned* __restrict__ ep4,
                             const float* __restrict__ e1w,
                             const float* __restrict__ e1b,
                             const float* __restrict__ w1aT,
                             const float* __restrict__ b1a,
                             const float* __restrict__ w1bT,
                             const float* __restrict__ b1b,
                             __half* __restrict__ h1lo,
                             __half* __restrict__ h1hi) {
    int n = blockIdx.x * (blockDim.x >> 6) + (threadIdx.x >> 6);
    int lane = threadIdx.x & 63;
    if (n >= N_NODES) return;
    int slot = lane >> 4;
    int f = lane & 15;
    int s0 = starts[n], dg = deg[n];
    bool act = f < F_IN;
    float wf = act ? e1w[f] : 0.f;
    float bf = act ? e1b[f] : 0.f;
    float acc = 0.f;
    int j = slot;
    for (; j + 12 < dg; j += 16) {
        unsigned pa = ep4[s0 + j];
        unsigned pb = ep4[s0 + j + 4];
        unsigned pc = ep4[s0 + j + 8];
        unsigned pd = ep4[s0 + j + 12];
        float xa_ = act ? x[(pa >> 16) * F_IN + f] : 0.f;
        float xb_ = act ? x[(pb >> 16) * F_IN + f] : 0.f;
        float xc_ = act ? x[(pc >> 16) * F_IN + f] : 0.f;
        float xd_ = act ? x[(pd >> 16) * F_IN + f] : 0.f;
        if (act) {
            acc += fmaxf(xa_ + UNPACK_ATTR(pa) * wf + bf, 0.f)
                 + fmaxf(xb_ + UNPACK_ATTR(pb) * wf + bf, 0.f)
                 + fmaxf(xc_ + UNPACK_ATTR(pc) * wf + bf, 0.f)
                 + fmaxf(xd_ + UNPACK_ATTR(pd) * wf + bf, 0.f);
        }
    }
    for (; j < dg; j += 4) {
        unsigned p = ep4[s0 + j];
        float xv = act ? x[(p >> 16) * F_IN + f] : 0.f;
        float m = xv + UNPACK_ATTR(p) * wf + bf;
        acc += act ? fmaxf(m, 0.f) : 0.f;
    }
    acc += __shfl_xor(acc, 16, 64);
    acc += __shfl_xor(acc, 32, 64);
    float xa = (lane < F_IN) ? x[n * F_IN + lane] + acc : 0.f;
    float a1 = b1a[lane];
#pragma unroll
    for (int k = 0; k < F_IN; ++k)
        a1 += __shfl(xa, k, 64) * w1aT[k * H + lane];
    float ha = fmaxf(a1, 0.f);
    float a2 = b1b[lane];
#pragma unroll 16
    for (int k = 0; k < H; ++k)
        a2 += __shfl(ha, k, 64) * w1bT[k * H + lane];
    __half hv = __float2half(fmaxf(a2, 0.f));
    if (lane < 32) h1lo[n * 32 + lane] = hv;
    else           h1hi[n * 32 + (lane - 32)] = hv;
}

// ---------- conv2 aggregation phase (own launch, 3.2MB half stays L2-resident);
// fuses h = h1 + agg and writes FP32 htot[n][64] slice ----------
__global__ void aggphase_kernel(const __half* __restrict__ harr,
                                const int* __restrict__ starts,
                                const int* __restrict__ deg,
                                const unsigned* __restrict__ ep4,
                                const float* __restrict__ ew,
                                const float* __restrict__ eb,
                                float* __restrict__ htot, int foff) {
    int n = blockIdx.x * (blockDim.x >> 6) + (threadIdx.x >> 6);
    int lane = threadIdx.x & 63;
    if (n >= N_NODES) return;
    int half = lane >> 5;
    int fh = lane & 31;
    int s0 = starts[n], dg = deg[n];
    const unsigned* ep = ep4 + s0;
    float wf = ew[fh], bf = eb[fh];
    float acc = 0.f;
    int j = 0;
#define EDGE1(P, V) acc += fmaxf((V) + UNPACK_ATTR(P) * wf + bf, 0.f)
    for (; j + 16 <= dg; j += 16) {
        unsigned p0 = ep[j +  0 + half], p1 = ep[j +  2 + half];
        unsigned p2 = ep[j +  4 + half], p3 = ep[j +  6 + half];
        unsigned p4 = ep[j +  8 + half], p5 = ep[j + 10 + half];
        unsigned p6 = ep[j + 12 + half], p7 = ep[j + 14 + half];
        float v0 = __half2float(harr[(p0 >> 16) * 32 + fh]);
        float v1 = __half2float(harr[(p1 >> 16) * 32 + fh]);
        float v2 = __half2float(harr[(p2 >> 16) * 32 + fh]);
        float v3 = __half2float(harr[(p3 >> 16) * 32 + fh]);
        float v4 = __half2float(harr[(p4 >> 16) * 32 + fh]);
        float v5 = __half2float(harr[(p5 >> 16) * 32 + fh]);
        float v6 = __half2float(harr[(p6 >> 16) * 32 + fh]);
        float v7 = __half2float(harr[(p7 >> 16) * 32 + fh]);
        EDGE1(p0, v0); EDGE1(p1, v1); EDGE1(p2, v2); EDGE1(p3, v3);
        EDGE1(p4, v4); EDGE1(p5, v5); EDGE1(p6, v6); EDGE1(p7, v7);
    }
    for (; j + 2 <= dg; j += 2) {
        unsigned p = ep[j + half];
        float v = __half2float(harr[(p >> 16) * 32 + fh]);
        EDGE1(p, v);
    }
    if (j < dg && half == 0) {
        unsigned p = ep[j];
        float v = __half2float(harr[(p >> 16) * 32 + fh]);
        EDGE1(p, v);
    }
#undef EDGE1
    acc += __shfl_xor(acc, 32, 64);
    if (half == 0) {
        float h1v = __half2float(harr[n * 32 + fh]);
        htot[(size_t)n * 64 + foff + fh] = h1v + acc;
    }
}

// split 8 fp32 values into hi/lo fp16 fragments
__device__ __forceinline__ void split8(const float* __restrict__ v,
                                       f16x8& hi, f16x8& lo) {
#pragma unroll
    for (int j = 0; j < 8; ++j) {
        _Float16 h = (_Float16)v[j];
        hi[j] = h;
        lo[j] = (_Float16)(v[j] - (float)h);
    }
}

// ---------- node2 via split-fp16 MFMA (fp32-grade precision): wave = 16 nodes ----------
__global__ void node2_kernel(const float* __restrict__ htot,
                             const __half* __restrict__ pkAh, const __half* __restrict__ pkAl,
                             const float* __restrict__ b2a,
                             const __half* __restrict__ pkBh, const __half* __restrict__ pkBl,
                             const float* __restrict__ b2b,
                             const __half* __restrict__ pkRh, const __half* __restrict__ pkRl,
                             const float* __restrict__ br1,
                             const float* __restrict__ wr2,
                             const float* __restrict__ br2,
                             const int* __restrict__ term,
                             const float* __restrict__ ccost,
                             const int* __restrict__ batch,
                             float* __restrict__ pi,
                             float* __restrict__ te) {
    __shared__ float hbuf[4][16][68];
    int wv = threadIdx.x >> 6;
    int lane = threadIdx.x & 63;
    int gwave = blockIdx.x * 4 + wv;
    bool active = gwave < (N_NODES / 16);     // 50000 = 16*3125 exactly
    int base = active ? gwave * 16 : 0;
    int m = lane & 15, q = lane >> 4;
    const _Float16* pAh = (const _Float16*)pkAh;
    const _Float16* pAl = (const _Float16*)pkAl;
    const _Float16* pBh = (const _Float16*)pkBh;
    const _Float16* pBl = (const _Float16*)pkBl;
    const _Float16* pRh = (const _Float16*)pkRh;
    const _Float16* pRl = (const _Float16*)pkRl;

#define TILE3(C, A0H, A0L, A1H, A1L, PH, PL, T) do {                          \
        f16x8 b0h = *(const f16x8*)((PH) + (((T) * 2 + 0) * 64 + lane) * 8);  \
        f16x8 b0l = *(const f16x8*)((PL) + (((T) * 2 + 0) * 64 + lane) * 8);  \
        f16x8 b1h = *(const f16x8*)((PH) + (((T) * 2 + 1) * 64 + lane) * 8);  \
        f16x8 b1l = *(const f16x8*)((PL) + (((T) * 2 + 1) * 64 + lane) * 8);  \
        C = __builtin_amdgcn_mfma_f32_16x16x32_f16(A0H, b0h, C, 0, 0, 0);     \
        C = __builtin_amdgcn_mfma_f32_16x16x32_f16(A0L, b0h, C, 0, 0, 0);     \
        C = __builtin_amdgcn_mfma_f32_16x16x32_f16(A0H, b0l, C, 0, 0, 0);     \
        C = __builtin_amdgcn_mfma_f32_16x16x32_f16(A1H, b1h, C, 0, 0, 0);     \
        C = __builtin_amdgcn_mfma_f32_16x16x32_f16(A1L, b1h, C, 0, 0, 0);     \
        C = __builtin_amdgcn_mfma_f32_16x16x32_f16(A1H, b1l, C, 0, 0, 0);     \
    } while (0)

    f16x8 a0h, a0l, a1h, a1l;
    {
        const float* hrow = htot + (size_t)(base + m) * 64;
        split8(hrow + q * 8, a0h, a0l);
        split8(hrow + 32 + q * 8, a1h, a1l);
    }
#pragma unroll
    for (int t = 0; t < 4; ++t) {
        f32x4 c = {0.f, 0.f, 0.f, 0.f};
        TILE3(c, a0h, a0l, a1h, a1l, pAh, pAl, t);
        float bias = b2a[t * 16 + m];
#pragma unroll
        for (int r = 0; r < 4; ++r)
            hbuf[wv][q * 4 + r][t * 16 + m] = fmaxf(c[r] + bias, 0.f);
    }
    __syncthreads();
    split8(&hbuf[wv][m][q * 8], a0h, a0l);
    split8(&hbuf[wv][m][32 + q * 8], a1h, a1l);
    float tmp[4][4];
#pragma unroll
    for (int t = 0; t < 4; ++t) {
        f32x4 c = {0.f, 0.f, 0.f, 0.f};
        TILE3(c, a0h, a0l, a1h, a1l, pBh, pBl, t);
        float bias = b2b[t * 16 + m];
#pragma unroll
        for (int r = 0; r < 4; ++r)
            tmp[t][r] = fmaxf(c[r] + bias, 0.f);
    }
    __syncthreads();
#pragma unroll
    for (int t = 0; t < 4; ++t)
#pragma unroll
        for (int r = 0; r < 4; ++r)
            hbuf[wv][q * 4 + r][t * 16 + m] = tmp[t][r];
    __syncthreads();
    split8(&hbuf[wv][m][q * 8], a0h, a0l);
    split8(&hbuf[wv][m][32 + q * 8], a1h, a1l);
    float partial[4] = {0.f, 0.f, 0.f, 0.f};
#pragma unroll
    for (int t = 0; t < 2; ++t) {
        f32x4 c = {0.f, 0.f, 0.f, 0.f};
        TILE3(c, a0h, a0l, a1h, a1l, pRh, pRl, t);
        float bias = br1[t * 16 + m];
        float wv2 = wr2[t * 16 + m];
#pragma unroll
        for (int r = 0; r < 4; ++r)
            partial[r] += fmaxf(c[r] + bias, 0.f) * wv2;
    }
#undef TILE3
#pragma unroll
    for (int off = 1; off < 16; off <<= 1) {
        partial[0] += __shfl_xor(partial[0], off, 64);
        partial[1] += __shfl_xor(partial[1], off, 64);
        partial[2] += __shfl_xor(partial[2], off, 64);
        partial[3] += __shfl_xor(partial[3], off, 64);
    }
    if (active && m == 0) {
#pragma unroll
        for (int r = 0; r < 4; ++r) {
            int n = base + q * 4 + r;
            float z = partial[r] + br2[0];
            float sig = 1.f / (1.f + expf(-z));
            float p = sig * (1.f - (float)term[n]);
            pi[n] = p;
            atomicAdd(&te[batch[n]], p * ccost[n]);
        }
    }
}

__global__ void final_kernel(const float* __restrict__ pi,
                             const int* __restrict__ batch,
                             const float* __restrict__ Btot,
                             const float* __restrict__ te,
                             float* __restrict__ out) {
    int n = blockIdx.x * blockDim.x + threadIdx.x;
    if (n >= N_NODES) return;
    int b = batch[n];
    float ratio = fminf(Btot[b] / (te[b] + 1e-12f), 1.f);
    out[n] = pi[n] * ratio;
}

extern "C" void kernel_launch(void* const* d_in, const int* in_sizes, int n_in,
                              void* d_out, int out_size, void* d_ws, size_t ws_size,
                              hipStream_t stream) {
    const float* x     = (const float*)d_in[0];
    const int*   ei    = (const int*)d_in[1];
    const float* ea    = (const float*)d_in[2];
    const int*   batch = (const int*)d_in[3];
    const float* Btot  = (const float*)d_in[4];
    const int*   term  = (const int*)d_in[5];
    const float* ccost = (const float*)d_in[6];
    const float* e1w   = (const float*)d_in[7];
    const float* e1b   = (const float*)d_in[8];
    const float* w1a   = (const float*)d_in[9];
    const float* b1a   = (const float*)d_in[10];
    const float* w1b   = (const float*)d_in[11];
    const float* b1b   = (const float*)d_in[12];
    const float* e2w   = (const float*)d_in[13];
    const float* e2b   = (const float*)d_in[14];
    const float* w2a   = (const float*)d_in[15];
    const float* b2a   = (const float*)d_in[16];
    const float* w2b   = (const float*)d_in[17];
    const float* b2b   = (const float*)d_in[18];
    const float* wr1   = (const float*)d_in[19];
    const float* br1   = (const float*)d_in[20];
    const float* wr2   = (const float*)d_in[21];
    const float* br2   = (const float*)d_in[22];

    char* p = (char*)d_ws;
    int*      bcnt   = (int*)p;      p += sizeof(int)      * 256;       // zeroed
    float*    te     = (float*)p;    p += sizeof(float)    * N_GRAPHS;  // zeroed
    int*      bbase  = (int*)p;      p += sizeof(int)      * 256;
    int*      bnext  = (int*)p;      p += sizeof(int)      * 256;
    int*      starts = (int*)p;      p += sizeof(int)      * N_NODES;
    int*      deg    = (int*)p;      p += sizeof(int)      * N_NODES;
    p = (char*)(((size_t)p + 15) & ~(size_t)15);
    uint2*    ebuk   = (uint2*)p;    p += sizeof(uint2)    * (size_t)N_EDGES;
    unsigned* ep4    = (unsigned*)p; p += sizeof(unsigned) * (size_t)N_EDGES;
    __half*   h1lo   = (__half*)p;   p += sizeof(__half)   * (size_t)N_NODES * 32;
    __half*   h1hi   = (__half*)p;   p += sizeof(__half)   * (size_t)N_NODES * 32;
    float*    htot   = (float*)p;    p += sizeof(float)    * (size_t)N_NODES * 64;
    float*    pi     = (float*)p;    p += sizeof(float)    * N_NODES;
    float*    w1aT   = (float*)p;    p += sizeof(float)    * F_IN * H;
    float*    w1bT   = (float*)p;    p += sizeof(float)    * H * H;
    __half*   pkAh   = (__half*)p;   p += sizeof(__half)   * 4096;
    __half*   pkAl   = (__half*)p;   p += sizeof(__half)   * 4096;
    __half*   pkBh   = (__half*)p;   p += sizeof(__half)   * 4096;
    __half*   pkBl   = (__half*)p;   p += sizeof(__half)   * 4096;
    __half*   pkRh   = (__half*)p;   p += sizeof(__half)   * 2048;
    __half*   pkRl   = (__half*)p;   p += sizeof(__half)   * 2048;
    float*    out    = (float*)d_out;

    hipMemsetAsync(d_ws, 0, sizeof(int) * 256 + sizeof(float) * N_GRAPHS, stream);

    pack_weights<<<1, 256, 0, stream>>>(w1a, w1b, w2a, w2b, wr1, w1aT, w1bT,
                                        pkAh, pkAl, pkBh, pkBl, pkRh, pkRl);
    bucket_hist<<<(N_EDGES / 4 + 255) / 256, 256, 0, stream>>>(ei, bcnt);
    bucket_scan<<<1, 256, 0, stream>>>(bcnt, bbase, bnext);
    bucket_scatter<<<N_SBLK, 256, 0, stream>>>(ei, ea, bnext, ebuk);
    bucket_fine<<<N_BUCKETS, 256, 0, stream>>>(ebuk, bbase, bcnt, ep4, starts, deg);
    conv1_kernel<<<(N_NODES + 3) / 4, 256, 0, stream>>>(x, starts, deg, ep4,
                                                        e1w, e1b, w1aT, b1a, w1bT, b1b,
                                                        h1lo, h1hi);
    aggphase_kernel<<<(N_NODES + 3) / 4, 256, 0, stream>>>(h1lo, starts, deg, ep4,
                                                           e2w, e2b, htot, 0);
    aggphase_kernel<<<(N_NODES + 3) / 4, 256, 0, stream>>>(h1hi, starts, deg, ep4,
                                                           e2w + 32, e2b + 32, htot, 32);
    node2_kernel<<<(N_NODES / 16 + 3) / 4, 256, 0, stream>>>(htot,
                                                             pkAh, pkAl, b2a,
                                                             pkBh, pkBl, b2b,
                                                             pkRh, pkRl, br1,
                                                             wr2, br2,
                                                             term, ccost, batch, pi, te);
    final_kernel<<<(N_NODES + 255) / 256, 256, 0, stream>>>(pi, batch, Btot, te, out);
}

// Round 14
// 306.590 us; speedup vs baseline: 1.8112x; 1.1911x over previous
//
#include <hip/hip_runtime.h>
#include <hip/hip_fp16.h>
#include <math.h>

#define N_NODES 50000
#define N_EDGES 1600000
#define N_GRAPHS 512
#define F_IN 9
#define H 64
#define N_BUCKETS ((N_NODES + 255) >> 8)     // 196
#define EPB 8192
#define N_SBLK ((N_EDGES + EPB - 1) / EPB)   // 196
#define FINE_CAP 10240

typedef _Float16 f16x8 __attribute__((ext_vector_type(8)));
typedef float f32x4 __attribute__((ext_vector_type(4)));

// ---------- weight packing (1 block) ----------
__global__ void pack_weights(const float* __restrict__ w1a,
                             const float* __restrict__ w1b,
                             const float* __restrict__ w2a,
                             const float* __restrict__ w2b,
                             const float* __restrict__ wr1,
                             __half* __restrict__ pk1Ah, __half* __restrict__ pk1Al,
                             __half* __restrict__ pk1Bh, __half* __restrict__ pk1Bl,
                             __half* __restrict__ pkAh, __half* __restrict__ pkAl,
                             __half* __restrict__ pkBh, __half* __restrict__ pkBl,
                             __half* __restrict__ pkRh, __half* __restrict__ pkRl) {
    int t = threadIdx.x;
    // w1a: [64][9] -> B-frag, K=32 zero-padded, single chunk
    for (int i = t; i < 2048; i += 256) {
        int j = i & 7, l = (i >> 3) & 63, tt = i >> 9;
        int q = l >> 4, n = l & 15;
        int k = q * 8 + j;
        float v = (k < F_IN) ? w1a[(tt * 16 + n) * F_IN + k] : 0.f;
        __half h = __float2half(v);
        pk1Ah[i] = h; pk1Al[i] = __float2half(v - __half2float(h));
    }
    for (int i = t; i < 4096; i += 256) {
        int j = i & 7, l = (i >> 3) & 63, c = (i >> 9) & 1, tt = i >> 10;
        int q = l >> 4, n = l & 15;
        int src = (tt * 16 + n) * H + c * 32 + q * 8 + j;
        float v1 = w1b[src], wa = w2a[src], wb = w2b[src];
        __half h1 = __float2half(v1), ah = __float2half(wa), bh = __float2half(wb);
        pk1Bh[i] = h1; pk1Bl[i] = __float2half(v1 - __half2float(h1));
        pkAh[i] = ah; pkAl[i] = __float2half(wa - __half2float(ah));
        pkBh[i] = bh; pkBl[i] = __float2half(wb - __half2float(bh));
    }
    for (int i = t; i < 2048; i += 256) {
        int j = i & 7, l = (i >> 3) & 63, c = (i >> 9) & 1, tt = i >> 10;
        int q = l >> 4, n = l & 15;
        float wr = wr1[(tt * 16 + n) * H + c * 32 + q * 8 + j];
        __half rh = __float2half(wr);
        pkRh[i] = rh; pkRl[i] = __float2half(wr - __half2float(rh));
    }
}

// ---------- bucket histogram ----------
__global__ void bucket_hist(const int* __restrict__ ei, int* __restrict__ bcnt) {
    __shared__ int h[N_BUCKETS];
    for (int i = threadIdx.x; i < N_BUCKETS; i += 256) h[i] = 0;
    __syncthreads();
    int t = blockIdx.x * 256 + threadIdx.x;
    if (t < N_EDGES / 4) {
        int4 d4 = ((const int4*)(ei + N_EDGES))[t];
        atomicAdd(&h[d4.x >> 8], 1);
        atomicAdd(&h[d4.y >> 8], 1);
        atomicAdd(&h[d4.z >> 8], 1);
        atomicAdd(&h[d4.w >> 8], 1);
    }
    __syncthreads();
    for (int i = threadIdx.x; i < N_BUCKETS; i += 256)
        if (h[i]) atomicAdd(&bcnt[i], h[i]);
}

__global__ void bucket_scan(const int* __restrict__ bcnt,
                            int* __restrict__ bbase, int* __restrict__ bnext) {
    __shared__ int wsum[4];
    int tid = threadIdx.x, lane = tid & 63, wid = tid >> 6;
    int v = (tid < N_BUCKETS) ? bcnt[tid] : 0;
    int incl = v;
#pragma unroll
    for (int off = 1; off < 64; off <<= 1) {
        int t = __shfl_up(incl, off, 64);
        if (lane >= off) incl += t;
    }
    if (lane == 63) wsum[wid] = incl;
    __syncthreads();
    int off = 0;
    for (int w = 0; w < wid; ++w) off += wsum[w];
    int excl = off + incl - v;
    if (tid < N_BUCKETS) { bbase[tid] = excl; bnext[tid] = excl; }
}

__global__ void bucket_scatter(const int* __restrict__ ei,
                               const float* __restrict__ ea,
                               int* __restrict__ bnext,
                               uint2* __restrict__ ebuk) {
    __shared__ int cnt[N_BUCKETS];
    __shared__ int gbase[N_BUCKETS];
    for (int i = threadIdx.x; i < N_BUCKETS; i += 256) cnt[i] = 0;
    __syncthreads();
    int base = blockIdx.x * EPB;
    int rk[32];
#pragma unroll
    for (int j = 0; j < 32; ++j) {
        int e = base + j * 256 + threadIdx.x;
        rk[j] = -1;
        if (e < N_EDGES) {
            int d = ei[N_EDGES + e];
            int b = d >> 8;
            int r = atomicAdd(&cnt[b], 1);
            rk[j] = (b << 21) | ((d & 255) << 13) | r;
        }
    }
    __syncthreads();
    for (int i = threadIdx.x; i < N_BUCKETS; i += 256)
        gbase[i] = cnt[i] ? atomicAdd(&bnext[i], cnt[i]) : 0;
    __syncthreads();
#pragma unroll
    for (int j = 0; j < 32; ++j) {
        if (rk[j] < 0) continue;
        int e = base + j * 256 + threadIdx.x;
        int b = rk[j] >> 21, dl = (rk[j] >> 13) & 255, r = rk[j] & 8191;
        unsigned pay = ((unsigned)ei[e] << 16) |
                       (unsigned)__half_as_ushort(__float2half(ea[e]));
        ebuk[gbase[b] + r] = make_uint2(pay, (unsigned)dl);
    }
}

__global__ void __launch_bounds__(256)
bucket_fine(const uint2* __restrict__ ebuk,
            const int* __restrict__ bbase, const int* __restrict__ bcnt,
            unsigned* __restrict__ ep4,
            int* __restrict__ starts, int* __restrict__ deg) {
    __shared__ unsigned sorted[FINE_CAP];
    __shared__ int cntN[256], offN[256], nxtN[256];
    __shared__ int wsum[4];
    int b = blockIdx.x;
    int base = bbase[b];
    int count = bcnt[b];
    if (count > FINE_CAP) count = FINE_CAP;
    int tid = threadIdx.x;
    cntN[tid] = 0;
    __syncthreads();
    for (int i = tid; i < count; i += 256)
        atomicAdd(&cntN[ebuk[base + i].y], 1);
    __syncthreads();
    int lane = tid & 63, wid = tid >> 6;
    int v = cntN[tid], incl = v;
#pragma unroll
    for (int off = 1; off < 64; off <<= 1) {
        int t = __shfl_up(incl, off, 64);
        if (lane >= off) incl += t;
    }
    if (lane == 63) wsum[wid] = incl;
    __syncthreads();
    int woff = 0;
    for (int w = 0; w < wid; ++w) woff += wsum[w];
    int excl = woff + incl - v;
    offN[tid] = excl;
    nxtN[tid] = 0;
    int n = (b << 8) + tid;
    if (n < N_NODES) { starts[n] = base + excl; deg[n] = v; }
    __syncthreads();
    for (int i = tid; i < count; i += 256) {
        uint2 e = ebuk[base + i];
        int r = atomicAdd(&nxtN[e.y], 1);
        sorted[offN[e.y] + r] = e.x;
    }
    __syncthreads();
    for (int i = tid; i < count; i += 256)
        ep4[base + i] = sorted[i];
}

#define UNPACK_ATTR(P) __half2float(__ushort_as_half((unsigned short)((P) & 0xffffu)))

// ---------- conv1 aggregation only: writes xs[n][32] = (x + agg, zero-padded) ----------
__global__ void agg1_kernel(const float* __restrict__ x,
                            const int* __restrict__ starts,
                            const int* __restrict__ deg,
                            const unsigned* __restrict__ ep4,
                            const float* __restrict__ e1w,
                            const float* __restrict__ e1b,
                            float* __restrict__ xs) {
    int n = blockIdx.x * (blockDim.x >> 6) + (threadIdx.x >> 6);
    int lane = threadIdx.x & 63;
    if (n >= N_NODES) return;
    int slot = lane >> 4;
    int f = lane & 15;
    int s0 = starts[n], dg = deg[n];
    bool act = f < F_IN;
    float wf = act ? e1w[f] : 0.f;
    float bf = act ? e1b[f] : 0.f;
    float acc = 0.f;
    int j = slot;
    for (; j + 12 < dg; j += 16) {
        unsigned pa = ep4[s0 + j];
        unsigned pb = ep4[s0 + j + 4];
        unsigned pc = ep4[s0 + j + 8];
        unsigned pd = ep4[s0 + j + 12];
        float xa_ = act ? x[(pa >> 16) * F_IN + f] : 0.f;
        float xb_ = act ? x[(pb >> 16) * F_IN + f] : 0.f;
        float xc_ = act ? x[(pc >> 16) * F_IN + f] : 0.f;
        float xd_ = act ? x[(pd >> 16) * F_IN + f] : 0.f;
        if (act) {
            acc += fmaxf(xa_ + UNPACK_ATTR(pa) * wf + bf, 0.f)
                 + fmaxf(xb_ + UNPACK_ATTR(pb) * wf + bf, 0.f)
                 + fmaxf(xc_ + UNPACK_ATTR(pc) * wf + bf, 0.f)
                 + fmaxf(xd_ + UNPACK_ATTR(pd) * wf + bf, 0.f);
        }
    }
    for (; j < dg; j += 4) {
        unsigned p = ep4[s0 + j];
        float xv = act ? x[(p >> 16) * F_IN + f] : 0.f;
        float m = xv + UNPACK_ATTR(p) * wf + bf;
        acc += act ? fmaxf(m, 0.f) : 0.f;
    }
    acc += __shfl_xor(acc, 16, 64);
    acc += __shfl_xor(acc, 32, 64);
    if (lane < 32)
        xs[n * 32 + lane] = (lane < F_IN) ? x[n * F_IN + lane] + acc : 0.f;
}

// split 8 fp32 values into hi/lo fp16 fragments
__device__ __forceinline__ void split8(const float* __restrict__ v,
                                       f16x8& hi, f16x8& lo) {
#pragma unroll
    for (int j = 0; j < 8; ++j) {
        _Float16 h = (_Float16)v[j];
        hi[j] = h;
        lo[j] = (_Float16)(v[j] - (float)h);
    }
}

#define TILE3(C, A0H, A0L, A1H, A1L, PH, PL, T) do {                          \
        f16x8 b0h = *(const f16x8*)((PH) + (((T) * 2 + 0) * 64 + lane) * 8);  \
        f16x8 b0l = *(const f16x8*)((PL) + (((T) * 2 + 0) * 64 + lane) * 8);  \
        f16x8 b1h = *(const f16x8*)((PH) + (((T) * 2 + 1) * 64 + lane) * 8);  \
        f16x8 b1l = *(const f16x8*)((PL) + (((T) * 2 + 1) * 64 + lane) * 8);  \
        C = __builtin_amdgcn_mfma_f32_16x16x32_f16(A0H, b0h, C, 0, 0, 0);     \
        C = __builtin_amdgcn_mfma_f32_16x16x32_f16(A0L, b0h, C, 0, 0, 0);     \
        C = __builtin_amdgcn_mfma_f32_16x16x32_f16(A0H, b0l, C, 0, 0, 0);     \
        C = __builtin_amdgcn_mfma_f32_16x16x32_f16(A1H, b1h, C, 0, 0, 0);     \
        C = __builtin_amdgcn_mfma_f32_16x16x32_f16(A1L, b1h, C, 0, 0, 0);     \
        C = __builtin_amdgcn_mfma_f32_16x16x32_f16(A1H, b1l, C, 0, 0, 0);     \
    } while (0)

// ---------- conv1 node MLP via split-fp16 MFMA: wave = 16 nodes ----------
__global__ void node1_kernel(const float* __restrict__ xs,
                             const __half* __restrict__ pk1Ah, const __half* __restrict__ pk1Al,
                             const float* __restrict__ b1a,
                             const __half* __restrict__ pk1Bh, const __half* __restrict__ pk1Bl,
                             const float* __restrict__ b1b,
                             __half* __restrict__ h1lo,
                             __half* __restrict__ h1hi) {
    __shared__ float hbuf[4][16][68];
    int wv = threadIdx.x >> 6;
    int lane = threadIdx.x & 63;
    int gwave = blockIdx.x * 4 + wv;
    bool active = gwave < (N_NODES / 16);
    int base = active ? gwave * 16 : 0;
    int m = lane & 15, q = lane >> 4;
    const _Float16* pAh = (const _Float16*)pk1Ah;
    const _Float16* pAl = (const _Float16*)pk1Al;
    const _Float16* pBh = (const _Float16*)pk1Bh;
    const _Float16* pBl = (const _Float16*)pk1Bl;

    // layer A: K=32 single chunk
    f16x8 ah, al;
    split8(xs + (size_t)(base + m) * 32 + q * 8, ah, al);
#pragma unroll
    for (int t = 0; t < 4; ++t) {
        f32x4 c = {0.f, 0.f, 0.f, 0.f};
        f16x8 bh = *(const f16x8*)(pAh + (t * 64 + lane) * 8);
        f16x8 bl = *(const f16x8*)(pAl + (t * 64 + lane) * 8);
        c = __builtin_amdgcn_mfma_f32_16x16x32_f16(ah, bh, c, 0, 0, 0);
        c = __builtin_amdgcn_mfma_f32_16x16x32_f16(al, bh, c, 0, 0, 0);
        c = __builtin_amdgcn_mfma_f32_16x16x32_f16(ah, bl, c, 0, 0, 0);
        float bias = b1a[t * 16 + m];
#pragma unroll
        for (int r = 0; r < 4; ++r)
            hbuf[wv][q * 4 + r][t * 16 + m] = fmaxf(c[r] + bias, 0.f);
    }
    __syncthreads();
    // layer B: K=64
    f16x8 a0h, a0l, a1h, a1l;
    split8(&hbuf[wv][m][q * 8], a0h, a0l);
    split8(&hbuf[wv][m][32 + q * 8], a1h, a1l);
    float tmp[4][4];
#pragma unroll
    for (int t = 0; t < 4; ++t) {
        f32x4 c = {0.f, 0.f, 0.f, 0.f};
        TILE3(c, a0h, a0l, a1h, a1l, pBh, pBl, t);
        float bias = b1b[t * 16 + m];
#pragma unroll
        for (int r = 0; r < 4; ++r)
            tmp[t][r] = fmaxf(c[r] + bias, 0.f);
    }
    __syncthreads();
#pragma unroll
    for (int t = 0; t < 4; ++t)
#pragma unroll
        for (int r = 0; r < 4; ++r)
            hbuf[wv][q * 4 + r][t * 16 + m] = tmp[t][r];
    __syncthreads();
    if (active) {
        int nn = lane >> 2, part = lane & 3;   // lane -> (node, quarter)
        f16x8 vlo, vhi;
        const float* rlo = &hbuf[wv][nn][part * 8];
        const float* rhi = &hbuf[wv][nn][32 + part * 8];
#pragma unroll
        for (int j = 0; j < 8; ++j) {
            vlo[j] = (_Float16)rlo[j];
            vhi[j] = (_Float16)rhi[j];
        }
        *(f16x8*)(h1lo + (size_t)(base + nn) * 32 + part * 8) = vlo;
        *(f16x8*)(h1hi + (size_t)(base + nn) * 32 + part * 8) = vhi;
    }
}

// ---------- conv2 aggregation phase (L2-resident half) -> fp32 htot slice ----------
__global__ void aggphase_kernel(const __half* __restrict__ harr,
                                const int* __restrict__ starts,
                                const int* __restrict__ deg,
                                const unsigned* __restrict__ ep4,
                                const float* __restrict__ ew,
                                const float* __restrict__ eb,
                                float* __restrict__ htot, int foff) {
    int n = blockIdx.x * (blockDim.x >> 6) + (threadIdx.x >> 6);
    int lane = threadIdx.x & 63;
    if (n >= N_NODES) return;
    int half = lane >> 5;
    int fh = lane & 31;
    int s0 = starts[n], dg = deg[n];
    const unsigned* ep = ep4 + s0;
    float wf = ew[fh], bf = eb[fh];
    float acc = 0.f;
    int j = 0;
#define EDGE1(P, V) acc += fmaxf((V) + UNPACK_ATTR(P) * wf + bf, 0.f)
    for (; j + 16 <= dg; j += 16) {
        unsigned p0 = ep[j +  0 + half], p1 = ep[j +  2 + half];
        unsigned p2 = ep[j +  4 + half], p3 = ep[j +  6 + half];
        unsigned p4 = ep[j +  8 + half], p5 = ep[j + 10 + half];
        unsigned p6 = ep[j + 12 + half], p7 = ep[j + 14 + half];
        float v0 = __half2float(harr[(p0 >> 16) * 32 + fh]);
        float v1 = __half2float(harr[(p1 >> 16) * 32 + fh]);
        float v2 = __half2float(harr[(p2 >> 16) * 32 + fh]);
        float v3 = __half2float(harr[(p3 >> 16) * 32 + fh]);
        float v4 = __half2float(harr[(p4 >> 16) * 32 + fh]);
        float v5 = __half2float(harr[(p5 >> 16) * 32 + fh]);
        float v6 = __half2float(harr[(p6 >> 16) * 32 + fh]);
        float v7 = __half2float(harr[(p7 >> 16) * 32 + fh]);
        EDGE1(p0, v0); EDGE1(p1, v1); EDGE1(p2, v2); EDGE1(p3, v3);
        EDGE1(p4, v4); EDGE1(p5, v5); EDGE1(p6, v6); EDGE1(p7, v7);
    }
    for (; j + 2 <= dg; j += 2) {
        unsigned p = ep[j + half];
        float v = __half2float(harr[(p >> 16) * 32 + fh]);
        EDGE1(p, v);
    }
    if (j < dg && half == 0) {
        unsigned p = ep[j];
        float v = __half2float(harr[(p >> 16) * 32 + fh]);
        EDGE1(p, v);
    }
#undef EDGE1
    acc += __shfl_xor(acc, 32, 64);
    if (half == 0) {
        float h1v = __half2float(harr[n * 32 + fh]);
        htot[(size_t)n * 64 + foff + fh] = h1v + acc;
    }
}

// ---------- node2 via split-fp16 MFMA; writes pi only (no atomics) ----------
__global__ void node2_kernel(const float* __restrict__ htot,
                             const __half* __restrict__ pkAh, const __half* __restrict__ pkAl,
                             const float* __restrict__ b2a,
                             const __half* __restrict__ pkBh, const __half* __restrict__ pkBl,
                             const float* __restrict__ b2b,
                             const __half* __restrict__ pkRh, const __half* __restrict__ pkRl,
                             const float* __restrict__ br1,
                             const float* __restrict__ wr2,
                             const float* __restrict__ br2,
                             const int* __restrict__ term,
                             float* __restrict__ pi) {
    __shared__ float hbuf[4][16][68];
    int wv = threadIdx.x >> 6;
    int lane = threadIdx.x & 63;
    int gwave = blockIdx.x * 4 + wv;
    bool active = gwave < (N_NODES / 16);
    int base = active ? gwave * 16 : 0;
    int m = lane & 15, q = lane >> 4;
    const _Float16* pAh = (const _Float16*)pkAh;
    const _Float16* pAl = (const _Float16*)pkAl;
    const _Float16* pBh = (const _Float16*)pkBh;
    const _Float16* pBl = (const _Float16*)pkBl;
    const _Float16* pRh = (const _Float16*)pkRh;
    const _Float16* pRl = (const _Float16*)pkRl;

    f16x8 a0h, a0l, a1h, a1l;
    {
        const float* hrow = htot + (size_t)(base + m) * 64;
        split8(hrow + q * 8, a0h, a0l);
        split8(hrow + 32 + q * 8, a1h, a1l);
    }
#pragma unroll
    for (int t = 0; t < 4; ++t) {
        f32x4 c = {0.f, 0.f, 0.f, 0.f};
        TILE3(c, a0h, a0l, a1h, a1l, pAh, pAl, t);
        float bias = b2a[t * 16 + m];
#pragma unroll
        for (int r = 0; r < 4; ++r)
            hbuf[wv][q * 4 + r][t * 16 + m] = fmaxf(c[r] + bias, 0.f);
    }
    __syncthreads();
    split8(&hbuf[wv][m][q * 8], a0h, a0l);
    split8(&hbuf[wv][m][32 + q * 8], a1h, a1l);
    float tmp[4][4];
#pragma unroll
    for (int t = 0; t < 4; ++t) {
        f32x4 c = {0.f, 0.f, 0.f, 0.f};
        TILE3(c, a0h, a0l, a1h, a1l, pBh, pBl, t);
        float bias = b2b[t * 16 + m];
#pragma unroll
        for (int r = 0; r < 4; ++r)
            tmp[t][r] = fmaxf(c[r] + bias, 0.f);
    }
    __syncthreads();
#pragma unroll
    for (int t = 0; t < 4; ++t)
#pragma unroll
        for (int r = 0; r < 4; ++r)
            hbuf[wv][q * 4 + r][t * 16 + m] = tmp[t][r];
    __syncthreads();
    split8(&hbuf[wv][m][q * 8], a0h, a0l);
    split8(&hbuf[wv][m][32 + q * 8], a1h, a1l);
    float partial[4] = {0.f, 0.f, 0.f, 0.f};
#pragma unroll
    for (int t = 0; t < 2; ++t) {
        f32x4 c = {0.f, 0.f, 0.f, 0.f};
        TILE3(c, a0h, a0l, a1h, a1l, pRh, pRl, t);
        float bias = br1[t * 16 + m];
        float wv2 = wr2[t * 16 + m];
#pragma unroll
        for (int r = 0; r < 4; ++r)
            partial[r] += fmaxf(c[r] + bias, 0.f) * wv2;
    }
#pragma unroll
    for (int off = 1; off < 16; off <<= 1) {
        partial[0] += __shfl_xor(partial[0], off, 64);
        partial[1] += __shfl_xor(partial[1], off, 64);
        partial[2] += __shfl_xor(partial[2], off, 64);
        partial[3] += __shfl_xor(partial[3], off, 64);
    }
    if (active && m == 0) {
#pragma unroll
        for (int r = 0; r < 4; ++r) {
            int n = base + q * 4 + r;
            float z = partial[r] + br2[0];
            float sig = 1.f / (1.f + expf(-z));
            pi[n] = sig * (1.f - (float)term[n]);
        }
    }
}

// ---------- segmented te reduction: batch is sorted -> ~10 graphs/block ----------
__global__ void te_kernel(const float* __restrict__ pi,
                          const float* __restrict__ ccost,
                          const int* __restrict__ batch,
                          float* __restrict__ te) {
    __shared__ float tg[N_GRAPHS];
    for (int i = threadIdx.x; i < N_GRAPHS; i += 1024) tg[i] = 0.f;
    __syncthreads();
    int n = blockIdx.x * 1024 + threadIdx.x;
    if (n < N_NODES) atomicAdd(&tg[batch[n]], pi[n] * ccost[n]);
    __syncthreads();
    for (int i = threadIdx.x; i < N_GRAPHS; i += 1024)
        if (tg[i] != 0.f) atomicAdd(&te[i], tg[i]);
}

__global__ void final_kernel(const float* __restrict__ pi,
                             const int* __restrict__ batch,
                             const float* __restrict__ Btot,
                             const float* __restrict__ te,
                             float* __restrict__ out) {
    int n = blockIdx.x * blockDim.x + threadIdx.x;
    if (n >= N_NODES) return;
    int b = batch[n];
    float ratio = fminf(Btot[b] / (te[b] + 1e-12f), 1.f);
    out[n] = pi[n] * ratio;
}

extern "C" void kernel_launch(void* const* d_in, const int* in_sizes, int n_in,
                              void* d_out, int out_size, void* d_ws, size_t ws_size,
                              hipStream_t stream) {
    const float* x     = (const float*)d_in[0];
    const int*   ei    = (const int*)d_in[1];
    const float* ea    = (const float*)d_in[2];
    const int*   batch = (const int*)d_in[3];
    const float* Btot  = (const float*)d_in[4];
    const int*   term  = (const int*)d_in[5];
    const float* ccost = (const float*)d_in[6];
    const float* e1w   = (const float*)d_in[7];
    const float* e1b   = (const float*)d_in[8];
    const float* w1a   = (const float*)d_in[9];
    const float* b1a   = (const float*)d_in[10];
    const float* w1b   = (const float*)d_in[11];
    const float* b1b   = (const float*)d_in[12];
    const float* e2w   = (const float*)d_in[13];
    const float* e2b   = (const float*)d_in[14];
    const float* w2a   = (const float*)d_in[15];
    const float* b2a   = (const float*)d_in[16];
    const float* w2b   = (const float*)d_in[17];
    const float* b2b   = (const float*)d_in[18];
    const float* wr1   = (const float*)d_in[19];
    const float* br1   = (const float*)d_in[20];
    const float* wr2   = (const float*)d_in[21];
    const float* br2   = (const float*)d_in[22];

    char* p = (char*)d_ws;
    int*      bcnt   = (int*)p;      p += sizeof(int)      * 256;       // zeroed
    float*    te     = (float*)p;    p += sizeof(float)    * N_GRAPHS;  // zeroed
    int*      bbase  = (int*)p;      p += sizeof(int)      * 256;
    int*      bnext  = (int*)p;      p += sizeof(int)      * 256;
    int*      starts = (int*)p;      p += sizeof(int)      * N_NODES;
    int*      deg    = (int*)p;      p += sizeof(int)      * N_NODES;
    p = (char*)(((size_t)p + 15) & ~(size_t)15);
    uint2*    ebuk   = (uint2*)p;    p += sizeof(uint2)    * (size_t)N_EDGES;
    unsigned* ep4    = (unsigned*)p; p += sizeof(unsigned) * (size_t)N_EDGES;
    __half*   h1lo   = (__half*)p;   p += sizeof(__half)   * (size_t)N_NODES * 32;
    __half*   h1hi   = (__half*)p;   p += sizeof(__half)   * (size_t)N_NODES * 32;
    float*    htot   = (float*)p;    p += sizeof(float)    * (size_t)N_NODES * 64;
    float*    xs     = (float*)p;    p += sizeof(float)    * (size_t)N_NODES * 32;
    float*    pi     = (float*)p;    p += sizeof(float)    * N_NODES;
    __half*   pk1Ah  = (__half*)p;   p += sizeof(__half)   * 2048;
    __half*   pk1Al  = (__half*)p;   p += sizeof(__half)   * 2048;
    __half*   pk1Bh  = (__half*)p;   p += sizeof(__half)   * 4096;
    __half*   pk1Bl  = (__half*)p;   p += sizeof(__half)   * 4096;
    __half*   pkAh   = (__half*)p;   p += sizeof(__half)   * 4096;
    __half*   pkAl   = (__half*)p;   p += sizeof(__half)   * 4096;
    __half*   pkBh   = (__half*)p;   p += sizeof(__half)   * 4096;
    __half*   pkBl   = (__half*)p;   p += sizeof(__half)   * 4096;
    __half*   pkRh   = (__half*)p;   p += sizeof(__half)   * 2048;
    __half*   pkRl   = (__half*)p;   p += sizeof(__half)   * 2048;
    float*    out    = (float*)d_out;

    hipMemsetAsync(d_ws, 0, sizeof(int) * 256 + sizeof(float) * N_GRAPHS, stream);

    pack_weights<<<1, 256, 0, stream>>>(w1a, w1b, w2a, w2b, wr1,
                                        pk1Ah, pk1Al, pk1Bh, pk1Bl,
                                        pkAh, pkAl, pkBh, pkBl, pkRh, pkRl);
    bucket_hist<<<(N_EDGES / 4 + 255) / 256, 256, 0, stream>>>(ei, bcnt);
    bucket_scan<<<1, 256, 0, stream>>>(bcnt, bbase, bnext);
    bucket_scatter<<<N_SBLK, 256, 0, stream>>>(ei, ea, bnext, ebuk);
    bucket_fine<<<N_BUCKETS, 256, 0, stream>>>(ebuk, bbase, bcnt, ep4, starts, deg);
    agg1_kernel<<<(N_NODES + 3) / 4, 256, 0, stream>>>(x, starts, deg, ep4, e1w, e1b, xs);
    node1_kernel<<<(N_NODES / 16 + 3) / 4, 256, 0, stream>>>(xs, pk1Ah, pk1Al, b1a,
                                                             pk1Bh, pk1Bl, b1b,
                                                             h1lo, h1hi);
    aggphase_kernel<<<(N_NODES + 3) / 4, 256, 0, stream>>>(h1lo, starts, deg, ep4,
                                                           e2w, e2b, htot, 0);
    aggphase_kernel<<<(N_NODES + 3) / 4, 256, 0, stream>>>(h1hi, starts, deg, ep4,
                                                           e2w + 32, e2b + 32, htot, 32);
    node2_kernel<<<(N_NODES / 16 + 3) / 4, 256, 0, stream>>>(htot,
                                                             pkAh, pkAl, b2a,
                                                             pkBh, pkBl, b2b,
                                                             pkRh, pkRl, br1,
                                                             wr2, br2, term, pi);
    te_kernel<<<(N_NODES + 1023) / 1024, 1024, 0, stream>>>(pi, ccost, batch, te);
    final_kernel<<<(N_NODES + 255) / 256, 256, 0, stream>>>(pi, batch, Btot, te, out);
}

// Round 15
// 264.193 us; speedup vs baseline: 2.1019x; 1.1605x over previous
//
#include <hip/hip_runtime.h>
#include <hip/hip_fp16.h>
#include <math.h>

#define N_NODES 50000
#define N_EDGES 1600000
#define N_GRAPHS 512
#define F_IN 9
#define H 64
#define N_BUCKETS ((N_NODES + 255) >> 8)     // 196
#define EPB 8192
#define N_SBLK ((N_EDGES + EPB - 1) / EPB)   // 196
#define FINE_CAP 10240                        // mean 8192, sd ~90 -> +22 sd

typedef _Float16 f16x8 __attribute__((ext_vector_type(8)));
typedef float f32x4 __attribute__((ext_vector_type(4)));

__device__ __forceinline__ void pack_weights_body(
        const float* __restrict__ w1a, const float* __restrict__ w1b,
        const float* __restrict__ w2a, const float* __restrict__ w2b,
        const float* __restrict__ wr1,
        __half* __restrict__ pk1Ah, __half* __restrict__ pk1Al,
        __half* __restrict__ pk1Bh, __half* __restrict__ pk1Bl,
        __half* __restrict__ pkAh, __half* __restrict__ pkAl,
        __half* __restrict__ pkBh, __half* __restrict__ pkBl,
        __half* __restrict__ pkRh, __half* __restrict__ pkRl) {
    int t = threadIdx.x;
    for (int i = t; i < 2048; i += 256) {      // w1a: [64][9], K=32 zero-pad
        int j = i & 7, l = (i >> 3) & 63, tt = i >> 9;
        int q = l >> 4, n = l & 15;
        int k = q * 8 + j;
        float v = (k < F_IN) ? w1a[(tt * 16 + n) * F_IN + k] : 0.f;
        __half h = __float2half(v);
        pk1Ah[i] = h; pk1Al[i] = __float2half(v - __half2float(h));
    }
    for (int i = t; i < 4096; i += 256) {
        int j = i & 7, l = (i >> 3) & 63, c = (i >> 9) & 1, tt = i >> 10;
        int q = l >> 4, n = l & 15;
        int src = (tt * 16 + n) * H + c * 32 + q * 8 + j;
        float v1 = w1b[src], wa = w2a[src], wb = w2b[src];
        __half h1 = __float2half(v1), ah = __float2half(wa), bh = __float2half(wb);
        pk1Bh[i] = h1; pk1Bl[i] = __float2half(v1 - __half2float(h1));
        pkAh[i] = ah; pkAl[i] = __float2half(wa - __half2float(ah));
        pkBh[i] = bh; pkBl[i] = __float2half(wb - __half2float(bh));
    }
    for (int i = t; i < 2048; i += 256) {
        int j = i & 7, l = (i >> 3) & 63, c = (i >> 9) & 1, tt = i >> 10;
        int q = l >> 4, n = l & 15;
        float wr = wr1[(tt * 16 + n) * H + c * 32 + q * 8 + j];
        __half rh = __float2half(wr);
        pkRh[i] = rh; pkRl[i] = __float2half(wr - __half2float(rh));
    }
}

// ---------- bucket scatter (fixed-capacity buckets, no hist/scan needed);
// block 0 packs weights instead ----------
__global__ void bucket_scatter(const int* __restrict__ ei,
                               const float* __restrict__ ea,
                               int* __restrict__ bnext,   // zero-init, per-bucket count
                               uint2* __restrict__ ebuk,
                               const float* __restrict__ w1a,
                               const float* __restrict__ w1b,
                               const float* __restrict__ w2a,
                               const float* __restrict__ w2b,
                               const float* __restrict__ wr1,
                               __half* pk1Ah, __half* pk1Al,
                               __half* pk1Bh, __half* pk1Bl,
                               __half* pkAh, __half* pkAl,
                               __half* pkBh, __half* pkBl,
                               __half* pkRh, __half* pkRl) {
    if (blockIdx.x == 0) {
        pack_weights_body(w1a, w1b, w2a, w2b, wr1, pk1Ah, pk1Al, pk1Bh, pk1Bl,
                          pkAh, pkAl, pkBh, pkBl, pkRh, pkRl);
        return;
    }
    __shared__ int cnt[N_BUCKETS];
    __shared__ int gbase[N_BUCKETS];
    for (int i = threadIdx.x; i < N_BUCKETS; i += 256) cnt[i] = 0;
    __syncthreads();
    int base = (blockIdx.x - 1) * EPB;
    int rk[32];   // (b<<21)|(dlocal<<13)|rank
#pragma unroll
    for (int j = 0; j < 32; ++j) {
        int e = base + j * 256 + threadIdx.x;
        rk[j] = -1;
        if (e < N_EDGES) {
            int d = ei[N_EDGES + e];
            int b = d >> 8;
            int r = atomicAdd(&cnt[b], 1);
            rk[j] = (b << 21) | ((d & 255) << 13) | r;
        }
    }
    __syncthreads();
    for (int i = threadIdx.x; i < N_BUCKETS; i += 256)
        gbase[i] = cnt[i] ? atomicAdd(&bnext[i], cnt[i]) : 0;
    __syncthreads();
#pragma unroll
    for (int j = 0; j < 32; ++j) {
        if (rk[j] < 0) continue;
        int e = base + j * 256 + threadIdx.x;
        int b = rk[j] >> 21, dl = (rk[j] >> 13) & 255, r = rk[j] & 8191;
        int slot = gbase[b] + r;
        if (slot >= FINE_CAP) continue;        // statistically unreachable guard
        unsigned pay = ((unsigned)ei[e] << 16) |
                       (unsigned)__half_as_ushort(__float2half(ea[e]));
        ebuk[(size_t)b * FINE_CAP + slot] = make_uint2(pay, (unsigned)dl);
    }
}

// ---------- per-bucket fine sort -> node CSR + node-sorted ep4 ----------
__global__ void __launch_bounds__(256)
bucket_fine(const uint2* __restrict__ ebuk,
            const int* __restrict__ bnext,
            unsigned* __restrict__ ep4,
            int* __restrict__ starts, int* __restrict__ deg) {
    __shared__ unsigned sorted[FINE_CAP];
    __shared__ int cntN[256], offN[256], nxtN[256];
    __shared__ int wsum[4];
    int b = blockIdx.x;
    int base = b * FINE_CAP;
    int count = bnext[b];
    if (count > FINE_CAP) count = FINE_CAP;
    int tid = threadIdx.x;
    cntN[tid] = 0;
    __syncthreads();
    for (int i = tid; i < count; i += 256)
        atomicAdd(&cntN[ebuk[base + i].y], 1);
    __syncthreads();
    int lane = tid & 63, wid = tid >> 6;
    int v = cntN[tid], incl = v;
#pragma unroll
    for (int off = 1; off < 64; off <<= 1) {
        int t = __shfl_up(incl, off, 64);
        if (lane >= off) incl += t;
    }
    if (lane == 63) wsum[wid] = incl;
    __syncthreads();
    int woff = 0;
    for (int w = 0; w < wid; ++w) woff += wsum[w];
    int excl = woff + incl - v;
    offN[tid] = excl;
    nxtN[tid] = 0;
    int n = (b << 8) + tid;
    if (n < N_NODES) { starts[n] = base + excl; deg[n] = v; }
    __syncthreads();
    for (int i = tid; i < count; i += 256) {
        uint2 e = ebuk[base + i];
        int r = atomicAdd(&nxtN[e.y], 1);
        sorted[offN[e.y] + r] = e.x;
    }
    __syncthreads();
    for (int i = tid; i < count; i += 256)
        ep4[base + i] = sorted[i];
}

#define UNPACK_ATTR(P) __half2float(__ushort_as_half((unsigned short)((P) & 0xffffu)))

// ---------- conv1 aggregation: writes xs[n][32] = (x + agg, zero-padded) ----------
__global__ void agg1_kernel(const float* __restrict__ x,
                            const int* __restrict__ starts,
                            const int* __restrict__ deg,
                            const unsigned* __restrict__ ep4,
                            const float* __restrict__ e1w,
                            const float* __restrict__ e1b,
                            float* __restrict__ xs) {
    int n = blockIdx.x * (blockDim.x >> 6) + (threadIdx.x >> 6);
    int lane = threadIdx.x & 63;
    if (n >= N_NODES) return;
    int slot = lane >> 4;
    int f = lane & 15;
    int s0 = starts[n], dg = deg[n];
    bool act = f < F_IN;
    float wf = act ? e1w[f] : 0.f;
    float bf = act ? e1b[f] : 0.f;
    float acc = 0.f;
    int j = slot;
    for (; j + 12 < dg; j += 16) {
        unsigned pa = ep4[s0 + j];
        unsigned pb = ep4[s0 + j + 4];
        unsigned pc = ep4[s0 + j + 8];
        unsigned pd = ep4[s0 + j + 12];
        float xa_ = act ? x[(pa >> 16) * F_IN + f] : 0.f;
        float xb_ = act ? x[(pb >> 16) * F_IN + f] : 0.f;
        float xc_ = act ? x[(pc >> 16) * F_IN + f] : 0.f;
        float xd_ = act ? x[(pd >> 16) * F_IN + f] : 0.f;
        if (act) {
            acc += fmaxf(xa_ + UNPACK_ATTR(pa) * wf + bf, 0.f)
                 + fmaxf(xb_ + UNPACK_ATTR(pb) * wf + bf, 0.f)
                 + fmaxf(xc_ + UNPACK_ATTR(pc) * wf + bf, 0.f)
                 + fmaxf(xd_ + UNPACK_ATTR(pd) * wf + bf, 0.f);
        }
    }
    for (; j < dg; j += 4) {
        unsigned p = ep4[s0 + j];
        float xv = act ? x[(p >> 16) * F_IN + f] : 0.f;
        float m = xv + UNPACK_ATTR(p) * wf + bf;
        acc += act ? fmaxf(m, 0.f) : 0.f;
    }
    acc += __shfl_xor(acc, 16, 64);
    acc += __shfl_xor(acc, 32, 64);
    if (lane < 32)
        xs[n * 32 + lane] = (lane < F_IN) ? x[n * F_IN + lane] + acc : 0.f;
}

__device__ __forceinline__ void split8(const float* __restrict__ v,
                                       f16x8& hi, f16x8& lo) {
#pragma unroll
    for (int j = 0; j < 8; ++j) {
        _Float16 h = (_Float16)v[j];
        hi[j] = h;
        lo[j] = (_Float16)(v[j] - (float)h);
    }
}

#define TILE3(C, A0H, A0L, A1H, A1L, PH, PL, T) do {                          \
        f16x8 b0h = *(const f16x8*)((PH) + (((T) * 2 + 0) * 64 + lane) * 8);  \
        f16x8 b0l = *(const f16x8*)((PL) + (((T) * 2 + 0) * 64 + lane) * 8);  \
        f16x8 b1h = *(const f16x8*)((PH) + (((T) * 2 + 1) * 64 + lane) * 8);  \
        f16x8 b1l = *(const f16x8*)((PL) + (((T) * 2 + 1) * 64 + lane) * 8);  \
        C = __builtin_amdgcn_mfma_f32_16x16x32_f16(A0H, b0h, C, 0, 0, 0);     \
        C = __builtin_amdgcn_mfma_f32_16x16x32_f16(A0L, b0h, C, 0, 0, 0);     \
        C = __builtin_amdgcn_mfma_f32_16x16x32_f16(A0H, b0l, C, 0, 0, 0);     \
        C = __builtin_amdgcn_mfma_f32_16x16x32_f16(A1H, b1h, C, 0, 0, 0);     \
        C = __builtin_amdgcn_mfma_f32_16x16x32_f16(A1L, b1h, C, 0, 0, 0);     \
        C = __builtin_amdgcn_mfma_f32_16x16x32_f16(A1H, b1l, C, 0, 0, 0);     \
    } while (0)

// ---------- conv1 node MLP via split-fp16 MFMA ----------
__global__ void node1_kernel(const float* __restrict__ xs,
                             const __half* __restrict__ pk1Ah, const __half* __restrict__ pk1Al,
                             const float* __restrict__ b1a,
                             const __half* __restrict__ pk1Bh, const __half* __restrict__ pk1Bl,
                             const float* __restrict__ b1b,
                             __half* __restrict__ h1lo,
                             __half* __restrict__ h1hi) {
    __shared__ float hbuf[4][16][68];
    int wv = threadIdx.x >> 6;
    int lane = threadIdx.x & 63;
    int gwave = blockIdx.x * 4 + wv;
    bool active = gwave < (N_NODES / 16);
    int base = active ? gwave * 16 : 0;
    int m = lane & 15, q = lane >> 4;
    const _Float16* pAh = (const _Float16*)pk1Ah;
    const _Float16* pAl = (const _Float16*)pk1Al;
    const _Float16* pBh = (const _Float16*)pk1Bh;
    const _Float16* pBl = (const _Float16*)pk1Bl;

    f16x8 ah, al;
    split8(xs + (size_t)(base + m) * 32 + q * 8, ah, al);
#pragma unroll
    for (int t = 0; t < 4; ++t) {
        f32x4 c = {0.f, 0.f, 0.f, 0.f};
        f16x8 bh = *(const f16x8*)(pAh + (t * 64 + lane) * 8);
        f16x8 bl = *(const f16x8*)(pAl + (t * 64 + lane) * 8);
        c = __builtin_amdgcn_mfma_f32_16x16x32_f16(ah, bh, c, 0, 0, 0);
        c = __builtin_amdgcn_mfma_f32_16x16x32_f16(al, bh, c, 0, 0, 0);
        c = __builtin_amdgcn_mfma_f32_16x16x32_f16(ah, bl, c, 0, 0, 0);
        float bias = b1a[t * 16 + m];
#pragma unroll
        for (int r = 0; r < 4; ++r)
            hbuf[wv][q * 4 + r][t * 16 + m] = fmaxf(c[r] + bias, 0.f);
    }
    __syncthreads();
    f16x8 a0h, a0l, a1h, a1l;
    split8(&hbuf[wv][m][q * 8], a0h, a0l);
    split8(&hbuf[wv][m][32 + q * 8], a1h, a1l);
    float tmp[4][4];
#pragma unroll
    for (int t = 0; t < 4; ++t) {
        f32x4 c = {0.f, 0.f, 0.f, 0.f};
        TILE3(c, a0h, a0l, a1h, a1l, pBh, pBl, t);
        float bias = b1b[t * 16 + m];
#pragma unroll
        for (int r = 0; r < 4; ++r)
            tmp[t][r] = fmaxf(c[r] + bias, 0.f);
    }
    __syncthreads();
#pragma unroll
    for (int t = 0; t < 4; ++t)
#pragma unroll
        for (int r = 0; r < 4; ++r)
            hbuf[wv][q * 4 + r][t * 16 + m] = tmp[t][r];
    __syncthreads();
    if (active) {
        int nn = lane >> 2, part = lane & 3;
        f16x8 vlo, vhi;
        const float* rlo = &hbuf[wv][nn][part * 8];
        const float* rhi = &hbuf[wv][nn][32 + part * 8];
#pragma unroll
        for (int j = 0; j < 8; ++j) {
            vlo[j] = (_Float16)rlo[j];
            vhi[j] = (_Float16)rhi[j];
        }
        *(f16x8*)(h1lo + (size_t)(base + nn) * 32 + part * 8) = vlo;
        *(f16x8*)(h1hi + (size_t)(base + nn) * 32 + part * 8) = vhi;
    }
}

// ---------- conv2 aggregation phase (L2-resident 3.2MB half) ----------
__global__ void aggphase_kernel(const __half* __restrict__ harr,
                                const int* __restrict__ starts,
                                const int* __restrict__ deg,
                                const unsigned* __restrict__ ep4,
                                const float* __restrict__ ew,
                                const float* __restrict__ eb,
                                float* __restrict__ htot, int foff) {
    int n = blockIdx.x * (blockDim.x >> 6) + (threadIdx.x >> 6);
    int lane = threadIdx.x & 63;
    if (n >= N_NODES) return;
    int half = lane >> 5;
    int fh = lane & 31;
    int s0 = starts[n], dg = deg[n];
    const unsigned* ep = ep4 + s0;
    float wf = ew[fh], bf = eb[fh];
    float acc = 0.f;
    int j = 0;
#define EDGE1(P, V) acc += fmaxf((V) + UNPACK_ATTR(P) * wf + bf, 0.f)
    for (; j + 16 <= dg; j += 16) {
        unsigned p0 = ep[j +  0 + half], p1 = ep[j +  2 + half];
        unsigned p2 = ep[j +  4 + half], p3 = ep[j +  6 + half];
        unsigned p4 = ep[j +  8 + half], p5 = ep[j + 10 + half];
        unsigned p6 = ep[j + 12 + half], p7 = ep[j + 14 + half];
        float v0 = __half2float(harr[(p0 >> 16) * 32 + fh]);
        float v1 = __half2float(harr[(p1 >> 16) * 32 + fh]);
        float v2 = __half2float(harr[(p2 >> 16) * 32 + fh]);
        float v3 = __half2float(harr[(p3 >> 16) * 32 + fh]);
        float v4 = __half2float(harr[(p4 >> 16) * 32 + fh]);
        float v5 = __half2float(harr[(p5 >> 16) * 32 + fh]);
        float v6 = __half2float(harr[(p6 >> 16) * 32 + fh]);
        float v7 = __half2float(harr[(p7 >> 16) * 32 + fh]);
        EDGE1(p0, v0); EDGE1(p1, v1); EDGE1(p2, v2); EDGE1(p3, v3);
        EDGE1(p4, v4); EDGE1(p5, v5); EDGE1(p6, v6); EDGE1(p7, v7);
    }
    for (; j + 2 <= dg; j += 2) {
        unsigned p = ep[j + half];
        float v = __half2float(harr[(p >> 16) * 32 + fh]);
        EDGE1(p, v);
    }
    if (j < dg && half == 0) {
        unsigned p = ep[j];
        float v = __half2float(harr[(p >> 16) * 32 + fh]);
        EDGE1(p, v);
    }
#undef EDGE1
    acc += __shfl_xor(acc, 32, 64);
    if (half == 0) {
        float h1v = __half2float(harr[n * 32 + fh]);
        htot[(size_t)n * 64 + foff + fh] = h1v + acc;
    }
}

// ---------- node2 via split-fp16 MFMA; writes pi only ----------
__global__ void node2_kernel(const float* __restrict__ htot,
                             const __half* __restrict__ pkAh, const __half* __restrict__ pkAl,
                             const float* __restrict__ b2a,
                             const __half* __restrict__ pkBh, const __half* __restrict__ pkBl,
                             const float* __restrict__ b2b,
                             const __half* __restrict__ pkRh, const __half* __restrict__ pkRl,
                             const float* __restrict__ br1,
                             const float* __restrict__ wr2,
                             const float* __restrict__ br2,
                             const int* __restrict__ term,
                             float* __restrict__ pi) {
    __shared__ float hbuf[4][16][68];
    int wv = threadIdx.x >> 6;
    int lane = threadIdx.x & 63;
    int gwave = blockIdx.x * 4 + wv;
    bool active = gwave < (N_NODES / 16);
    int base = active ? gwave * 16 : 0;
    int m = lane & 15, q = lane >> 4;
    const _Float16* pAh = (const _Float16*)pkAh;
    const _Float16* pAl = (const _Float16*)pkAl;
    const _Float16* pBh = (const _Float16*)pkBh;
    const _Float16* pBl = (const _Float16*)pkBl;
    const _Float16* pRh = (const _Float16*)pkRh;
    const _Float16* pRl = (const _Float16*)pkRl;

    f16x8 a0h, a0l, a1h, a1l;
    {
        const float* hrow = htot + (size_t)(base + m) * 64;
        split8(hrow + q * 8, a0h, a0l);
        split8(hrow + 32 + q * 8, a1h, a1l);
    }
#pragma unroll
    for (int t = 0; t < 4; ++t) {
        f32x4 c = {0.f, 0.f, 0.f, 0.f};
        TILE3(c, a0h, a0l, a1h, a1l, pAh, pAl, t);
        float bias = b2a[t * 16 + m];
#pragma unroll
        for (int r = 0; r < 4; ++r)
            hbuf[wv][q * 4 + r][t * 16 + m] = fmaxf(c[r] + bias, 0.f);
    }
    __syncthreads();
    split8(&hbuf[wv][m][q * 8], a0h, a0l);
    split8(&hbuf[wv][m][32 + q * 8], a1h, a1l);
    float tmp[4][4];
#pragma unroll
    for (int t = 0; t < 4; ++t) {
        f32x4 c = {0.f, 0.f, 0.f, 0.f};
        TILE3(c, a0h, a0l, a1h, a1l, pBh, pBl, t);
        float bias = b2b[t * 16 + m];
#pragma unroll
        for (int r = 0; r < 4; ++r)
            tmp[t][r] = fmaxf(c[r] + bias, 0.f);
    }
    __syncthreads();
#pragma unroll
    for (int t = 0; t < 4; ++t)
#pragma unroll
        for (int r = 0; r < 4; ++r)
            hbuf[wv][q * 4 + r][t * 16 + m] = tmp[t][r];
    __syncthreads();
    split8(&hbuf[wv][m][q * 8], a0h, a0l);
    split8(&hbuf[wv][m][32 + q * 8], a1h, a1l);
    float partial[4] = {0.f, 0.f, 0.f, 0.f};
#pragma unroll
    for (int t = 0; t < 2; ++t) {
        f32x4 c = {0.f, 0.f, 0.f, 0.f};
        TILE3(c, a0h, a0l, a1h, a1l, pRh, pRl, t);
        float bias = br1[t * 16 + m];
        float wv2 = wr2[t * 16 + m];
#pragma unroll
        for (int r = 0; r < 4; ++r)
            partial[r] += fmaxf(c[r] + bias, 0.f) * wv2;
    }
#pragma unroll
    for (int off = 1; off < 16; off <<= 1) {
        partial[0] += __shfl_xor(partial[0], off, 64);
        partial[1] += __shfl_xor(partial[1], off, 64);
        partial[2] += __shfl_xor(partial[2], off, 64);
        partial[3] += __shfl_xor(partial[3], off, 64);
    }
    if (active && m == 0) {
#pragma unroll
        for (int r = 0; r < 4; ++r) {
            int n = base + q * 4 + r;
            float z = partial[r] + br2[0];
            float sig = 1.f / (1.f + expf(-z));
            pi[n] = sig * (1.f - (float)term[n]);
        }
    }
}

// ---------- segmented te reduction (batch sorted) ----------
__global__ void te_kernel(const float* __restrict__ pi,
                          const float* __restrict__ ccost,
                          const int* __restrict__ batch,
                          float* __restrict__ te) {
    __shared__ float tg[N_GRAPHS];
    for (int i = threadIdx.x; i < N_GRAPHS; i += 1024) tg[i] = 0.f;
    __syncthreads();
    int n = blockIdx.x * 1024 + threadIdx.x;
    if (n < N_NODES) atomicAdd(&tg[batch[n]], pi[n] * ccost[n]);
    __syncthreads();
    for (int i = threadIdx.x; i < N_GRAPHS; i += 1024)
        if (tg[i] != 0.f) atomicAdd(&te[i], tg[i]);
}

__global__ void final_kernel(const float* __restrict__ pi,
                             const int* __restrict__ batch,
                             const float* __restrict__ Btot,
                             const float* __restrict__ te,
                             float* __restrict__ out) {
    int n = blockIdx.x * blockDim.x + threadIdx.x;
    if (n >= N_NODES) return;
    int b = batch[n];
    float ratio = fminf(Btot[b] / (te[b] + 1e-12f), 1.f);
    out[n] = pi[n] * ratio;
}

extern "C" void kernel_launch(void* const* d_in, const int* in_sizes, int n_in,
                              void* d_out, int out_size, void* d_ws, size_t ws_size,
                              hipStream_t stream) {
    const float* x     = (const float*)d_in[0];
    const int*   ei    = (const int*)d_in[1];
    const float* ea    = (const float*)d_in[2];
    const int*   batch = (const int*)d_in[3];
    const float* Btot  = (const float*)d_in[4];
    const int*   term  = (const int*)d_in[5];
    const float* ccost = (const float*)d_in[6];
    const float* e1w   = (const float*)d_in[7];
    const float* e1b   = (const float*)d_in[8];
    const float* w1a   = (const float*)d_in[9];
    const float* b1a   = (const float*)d_in[10];
    const float* w1b   = (const float*)d_in[11];
    const float* b1b   = (const float*)d_in[12];
    const float* e2w   = (const float*)d_in[13];
    const float* e2b   = (const float*)d_in[14];
    const float* w2a   = (const float*)d_in[15];
    const float* b2a   = (const float*)d_in[16];
    const float* w2b   = (const float*)d_in[17];
    const float* b2b   = (const float*)d_in[18];
    const float* wr1   = (const float*)d_in[19];
    const float* br1   = (const float*)d_in[20];
    const float* wr2   = (const float*)d_in[21];
    const float* br2   = (const float*)d_in[22];

    char* p = (char*)d_ws;
    int*      bnext  = (int*)p;      p += sizeof(int)      * 256;       // zeroed
    float*    te     = (float*)p;    p += sizeof(float)    * N_GRAPHS;  // zeroed
    int*      starts = (int*)p;      p += sizeof(int)      * N_NODES;
    int*      deg    = (int*)p;      p += sizeof(int)      * N_NODES;
    p = (char*)(((size_t)p + 15) & ~(size_t)15);
    uint2*    ebuk   = (uint2*)p;    p += sizeof(uint2)    * (size_t)N_BUCKETS * FINE_CAP;
    unsigned* ep4    = (unsigned*)p; p += sizeof(unsigned) * (size_t)N_BUCKETS * FINE_CAP;
    __half*   h1lo   = (__half*)p;   p += sizeof(__half)   * (size_t)N_NODES * 32;
    __half*   h1hi   = (__half*)p;   p += sizeof(__half)   * (size_t)N_NODES * 32;
    float*    htot   = (float*)p;    p += sizeof(float)    * (size_t)N_NODES * 64;
    float*    xs     = (float*)p;    p += sizeof(float)    * (size_t)N_NODES * 32;
    float*    pi     = (float*)p;    p += sizeof(float)    * N_NODES;
    __half*   pk1Ah  = (__half*)p;   p += sizeof(__half)   * 2048;
    __half*   pk1Al  = (__half*)p;   p += sizeof(__half)   * 2048;
    __half*   pk1Bh  = (__half*)p;   p += sizeof(__half)   * 4096;
    __half*   pk1Bl  = (__half*)p;   p += sizeof(__half)   * 4096;
    __half*   pkAh   = (__half*)p;   p += sizeof(__half)   * 4096;
    __half*   pkAl   = (__half*)p;   p += sizeof(__half)   * 4096;
    __half*   pkBh   = (__half*)p;   p += sizeof(__half)   * 4096;
    __half*   pkBl   = (__half*)p;   p += sizeof(__half)   * 4096;
    __half*   pkRh   = (__half*)p;   p += sizeof(__half)   * 2048;
    __half*   pkRl   = (__half*)p;   p += sizeof(__half)   * 2048;
    float*    out    = (float*)d_out;

    hipMemsetAsync(d_ws, 0, sizeof(int) * 256 + sizeof(float) * N_GRAPHS, stream);

    bucket_scatter<<<1 + N_SBLK, 256, 0, stream>>>(ei, ea, bnext, ebuk,
                                                   w1a, w1b, w2a, w2b, wr1,
                                                   pk1Ah, pk1Al, pk1Bh, pk1Bl,
                                                   pkAh, pkAl, pkBh, pkBl, pkRh, pkRl);
    bucket_fine<<<N_BUCKETS, 256, 0, stream>>>(ebuk, bnext, ep4, starts, deg);
    agg1_kernel<<<(N_NODES + 3) / 4, 256, 0, stream>>>(x, starts, deg, ep4, e1w, e1b, xs);
    node1_kernel<<<(N_NODES / 16 + 3) / 4, 256, 0, stream>>>(xs, pk1Ah, pk1Al, b1a,
                                                             pk1Bh, pk1Bl, b1b,
                                                             h1lo, h1hi);
    aggphase_kernel<<<(N_NODES + 3) / 4, 256, 0, stream>>>(h1lo, starts, deg, ep4,
                                                           e2w, e2b, htot, 0);
    aggphase_kernel<<<(N_NODES + 3) / 4, 256, 0, stream>>>(h1hi, starts, deg, ep4,
                                                           e2w + 32, e2b + 32, htot, 32);
    node2_kernel<<<(N_NODES / 16 + 3) / 4, 256, 0, stream>>>(htot,
                                                             pkAh, pkAl, b2a,
                                                             pkBh, pkBl, b2b,
                                                             pkRh, pkRl, br1,
                                                             wr2, br2, term, pi);
    te_kernel<<<(N_NODES + 1023) / 1024, 1024, 0, stream>>>(pi, ccost, batch, te);
    final_kernel<<<(N_NODES + 255) / 256, 256, 0, stream>>>(pi, batch, Btot, te, out);
}